// Round 1
// baseline (168.593 us; speedup 1.0000x reference)
//
#include <hip/hip_runtime.h>
#include <stdint.h>

#define B_   4
#define S_   2048
#define IN_  512
#define HID_ 512
#define NH_  8
#define HD_  64
#define M_   (B_*S_)   // 8192

typedef __attribute__((ext_vector_type(8))) short  short8;
typedef __attribute__((ext_vector_type(4))) short  short4v;
typedef __attribute__((ext_vector_type(4))) float  f32x4;
typedef __attribute__((ext_vector_type(8))) __bf16 bf16x8;

// fp32 -> bf16 bits, round-to-nearest-even
__device__ __forceinline__ unsigned short f2bf(float f) {
  union { float f; unsigned u; } v; v.f = f;
  unsigned r = (v.u + 0x7fffu + ((v.u >> 16) & 1u)) >> 16;
  return (unsigned short)r;
}

__device__ __forceinline__ f32x4 mfma_bf16(short8 a, short8 b, f32x4 c) {
  return __builtin_amdgcn_mfma_f32_16x16x32_bf16(
      __builtin_bit_cast(bf16x8, a), __builtin_bit_cast(bf16x8, b), c, 0, 0, 0);
}

// async global->LDS, 16B per lane; dst must be wave-uniform base (lane*16 auto)
__device__ __forceinline__ void gload_lds16(const void* g, void* l) {
  __builtin_amdgcn_global_load_lds(
      (__attribute__((address_space(1))) void*)g,
      (__attribute__((address_space(3))) void*)l, 16, 0, 0);
}

// ---------------- kernel 1: x (fp32) -> xb (bf16) ----------------
__global__ __launch_bounds__(256) void sa_convert_x(const float* __restrict__ x,
                                                    short* __restrict__ xb) {
  int i = (blockIdx.x * 256 + threadIdx.x) * 8;
  const float4* p = (const float4*)&x[i];
  float4 a = p[0], b2 = p[1];
  short8 r;
  r[0] = (short)f2bf(a.x);  r[1] = (short)f2bf(a.y);
  r[2] = (short)f2bf(a.z);  r[3] = (short)f2bf(a.w);
  r[4] = (short)f2bf(b2.x); r[5] = (short)f2bf(b2.y);
  r[6] = (short)f2bf(b2.z); r[7] = (short)f2bf(b2.w);
  *(short8*)&xb[i] = r;
}

// ---------------- kernel 2: W (512x512 fp32) -> Wt (bf16, transposed) ----------------
__global__ __launch_bounds__(256) void sa_transpose_w(const float* __restrict__ Wq,
                                                      const float* __restrict__ Wk,
                                                      const float* __restrict__ Wv,
                                                      const float* __restrict__ Wo,
                                                      short* __restrict__ Wt) {
  __shared__ float tile[32][33];
  const int z = blockIdx.z;
  const float* src = (z == 0) ? Wq : (z == 1) ? Wk : (z == 2) ? Wv : Wo;
  const int k0 = blockIdx.y * 32, n0 = blockIdx.x * 32;
  const int tx = threadIdx.x, ty = threadIdx.y;   // (32, 8)
  #pragma unroll
  for (int i = 0; i < 32; i += 8)
    tile[ty + i][tx] = src[(size_t)(k0 + ty + i) * 512 + n0 + tx];
  __syncthreads();
  short* dst = Wt + (size_t)z * 262144;
  #pragma unroll
  for (int i = 0; i < 32; i += 8)
    dst[(size_t)(n0 + ty + i) * 512 + k0 + tx] = (short)f2bf(tile[tx][ty + i]);
}

// ---------------- GEMM: C(8192x512) = A(8192x512,bf16) @ W(512x512) + bias ----------------
// MODE 0: A = xb, z = blockIdx.z in {0,1,2} selects Wq/Wk/Wv; writes Q/K (B,H,S,D) and Vt (B,H,D,S) bf16
// MODE 1: A = Ob, z = 3 (Wo); writes fp32 d_out with bo
template <int MODE>
__global__ __launch_bounds__(256) void sa_gemm(const short* __restrict__ Abuf,
                                               const short* __restrict__ Wt,
                                               const float* __restrict__ bias0,
                                               const float* __restrict__ bias1,
                                               const float* __restrict__ bias2,
                                               short* __restrict__ Qb,
                                               short* __restrict__ Kb,
                                               short* __restrict__ Vt,
                                               float* __restrict__ outp) {
  __shared__ __align__(16) short A_lds[128 * 64];
  __shared__ __align__(16) short B_lds[128 * 64];
  const int tid = threadIdx.x, lane = tid & 63, wave = tid >> 6;
  const int row0 = blockIdx.x * 128, col0 = blockIdx.y * 128;
  const int z = (MODE == 0) ? blockIdx.z : 3;
  const short* Bsrc = Wt + (size_t)z * 262144;   // [512 n][512 k]
  const int wr = wave >> 1, wc = wave & 1;

  f32x4 acc[4][4];
  const f32x4 zf = {0.f, 0.f, 0.f, 0.f};
  #pragma unroll
  for (int mi = 0; mi < 4; ++mi)
    #pragma unroll
    for (int ni = 0; ni < 4; ++ni) acc[mi][ni] = zf;

  for (int k0 = 0; k0 < 512; k0 += 64) {
    __syncthreads();
    // stage A(128x64) and B(128x64) tiles; XOR-swizzle applied to GLOBAL source (rule #21)
    #pragma unroll
    for (int j = 0; j < 4; ++j) {
      int chunk = j * 256 + wave * 64 + lane;   // 1024 chunks of 8 bf16
      int row = chunk >> 3;
      int cc = (chunk & 7) ^ (row & 7);
      gload_lds16(Abuf + (size_t)(row0 + row) * 512 + k0 + cc * 8,
                  &A_lds[(j * 256 + wave * 64) * 8]);
      gload_lds16(Bsrc + (size_t)(col0 + row) * 512 + k0 + cc * 8,
                  &B_lds[(j * 256 + wave * 64) * 8]);
    }
    __syncthreads();
    #pragma unroll
    for (int kk = 0; kk < 2; ++kk) {
      short8 af[4], bf[4];
      #pragma unroll
      for (int mi = 0; mi < 4; ++mi) {
        int r = wr * 64 + mi * 16 + (lane & 15);
        int cs = (kk * 4 + (lane >> 4)) ^ (r & 7);
        af[mi] = *(const short8*)&A_lds[r * 64 + cs * 8];
      }
      #pragma unroll
      for (int ni = 0; ni < 4; ++ni) {
        int r = wc * 64 + ni * 16 + (lane & 15);
        int cs = (kk * 4 + (lane >> 4)) ^ (r & 7);
        bf[ni] = *(const short8*)&B_lds[r * 64 + cs * 8];
      }
      #pragma unroll
      for (int mi = 0; mi < 4; ++mi)
        #pragma unroll
        for (int ni = 0; ni < 4; ++ni)
          acc[mi][ni] = mfma_bf16(af[mi], bf[ni], acc[mi][ni]);
    }
  }

  // epilogue: C row = row0+wr*64+mi*16+(lane>>4)*4+j ; col = col0+wc*64+ni*16+(lane&15)
  if (MODE == 0) {
    const float* bias = (z == 0) ? bias0 : (z == 1) ? bias1 : bias2;
    #pragma unroll
    for (int ni = 0; ni < 4; ++ni) {
      int n = col0 + wc * 64 + ni * 16 + (lane & 15);
      float bsv = bias[n];
      int hh = n >> 6, dd = n & 63;
      #pragma unroll
      for (int mi = 0; mi < 4; ++mi) {
        int rg = row0 + wr * 64 + mi * 16 + ((lane >> 4) << 2);
        int bb = rg >> 11, ss = rg & 2047;
        if (z <= 1) {
          short* dst = (z == 0) ? Qb : Kb;
          size_t base = ((size_t)(bb * NH_ + hh) << 17);
          #pragma unroll
          for (int j = 0; j < 4; ++j)
            dst[base + (size_t)(ss + j) * 64 + dd] = (short)f2bf(acc[mi][ni][j] + bsv);
        } else {
          size_t base = ((size_t)(bb * NH_ + hh) << 17) + (size_t)dd * 2048 + ss;
          short4v pk;
          #pragma unroll
          for (int j = 0; j < 4; ++j) pk[j] = (short)f2bf(acc[mi][ni][j] + bsv);
          *(short4v*)&Vt[base] = pk;
        }
      }
    }
  } else {
    #pragma unroll
    for (int ni = 0; ni < 4; ++ni) {
      int n = col0 + wc * 64 + ni * 16 + (lane & 15);
      float bsv = bias0[n];
      #pragma unroll
      for (int mi = 0; mi < 4; ++mi) {
        int rg = row0 + wr * 64 + mi * 16 + ((lane >> 4) << 2);
        #pragma unroll
        for (int j = 0; j < 4; ++j)
          outp[(size_t)(rg + j) * 512 + n] = acc[mi][ni][j] + bsv;
      }
    }
  }
}

// ---------------- kernel 4: flash attention ----------------
// grid (S/128, H, B), 256 threads; wave owns 32 q-rows. KBLK=64.
__global__ __launch_bounds__(256) void sa_attn(const short* __restrict__ Qb,
                                               const short* __restrict__ Kb,
                                               const short* __restrict__ Vt,
                                               short* __restrict__ Ob) {
  __shared__ __align__(16) short K_lds[64 * 64];
  __shared__ __align__(16) short V_lds[64 * 64];
  __shared__ __align__(16) short P_lds[4][32 * 64];
  const int tid = threadIdx.x, lane = tid & 63, wave = tid >> 6;
  const int h = blockIdx.y, b = blockIdx.z;
  const size_t bh = ((size_t)(b * NH_ + h)) << 17;   // *131072 elements
  const int q0 = blockIdx.x * 128 + wave * 32;

  // hoist Q fragments (A-operand): row=q0+mi*16+(lane&15), k=kk*32+(lane>>4)*8
  short8 qf[2][2];
  #pragma unroll
  for (int mi = 0; mi < 2; ++mi)
    #pragma unroll
    for (int kk = 0; kk < 2; ++kk)
      qf[mi][kk] = *(const short8*)&Qb[bh + (size_t)(q0 + mi * 16 + (lane & 15)) * 64 +
                                       kk * 32 + ((lane >> 4) * 8)];

  f32x4 o[2][4];
  float mrow[2][4], lrow[2][4];
  const f32x4 zf = {0.f, 0.f, 0.f, 0.f};
  #pragma unroll
  for (int mi = 0; mi < 2; ++mi) {
    #pragma unroll
    for (int ni = 0; ni < 4; ++ni) o[mi][ni] = zf;
    #pragma unroll
    for (int j = 0; j < 4; ++j) { mrow[mi][j] = -3.0e38f; lrow[mi][j] = 0.f; }
  }
  const float cf = 0.18033688011112042f;   // log2(e)/8

  for (int k0 = 0; k0 < S_; k0 += 64) {
    __syncthreads();
    // stage K tile (64 k-rows x 64 d) and Vt tile (64 d-rows x 64 s) with source pre-swizzle
    #pragma unroll
    for (int j = 0; j < 2; ++j) {
      int chunk = j * 256 + wave * 64 + lane;   // 512 chunks each
      int row = chunk >> 3;
      int cc = (chunk & 7) ^ (row & 7);
      gload_lds16(&Kb[bh + (size_t)(k0 + row) * 64 + cc * 8],
                  &K_lds[(j * 256 + wave * 64) * 8]);
      gload_lds16(&Vt[bh + (size_t)row * 2048 + k0 + cc * 8],
                  &V_lds[(j * 256 + wave * 64) * 8]);
    }
    __syncthreads();

    // QK^T: sc[mi][ni] = 16x16 tile, rows=q, cols=k-positions
    f32x4 sc[2][4];
    #pragma unroll
    for (int mi = 0; mi < 2; ++mi)
      #pragma unroll
      for (int ni = 0; ni < 4; ++ni) sc[mi][ni] = zf;
    #pragma unroll
    for (int kk = 0; kk < 2; ++kk) {
      short8 kf[4];
      #pragma unroll
      for (int ni = 0; ni < 4; ++ni) {
        int r = ni * 16 + (lane & 15);
        int cs = (kk * 4 + (lane >> 4)) ^ (r & 7);
        kf[ni] = *(const short8*)&K_lds[r * 64 + cs * 8];
      }
      #pragma unroll
      for (int mi = 0; mi < 2; ++mi)
        #pragma unroll
        for (int ni = 0; ni < 4; ++ni)
          sc[mi][ni] = mfma_bf16(qf[mi][kk], kf[ni], sc[mi][ni]);
    }

    // online softmax; row r = mi*16+(lane>>4)*4+j, replicated across 16-lane col groups
    #pragma unroll
    for (int mi = 0; mi < 2; ++mi)
      #pragma unroll
      for (int j = 0; j < 4; ++j) {
        float mx = fmaxf(fmaxf(sc[mi][0][j], sc[mi][1][j]),
                         fmaxf(sc[mi][2][j], sc[mi][3][j]));
        mx = fmaxf(mx, __shfl_xor(mx, 1, 16));
        mx = fmaxf(mx, __shfl_xor(mx, 2, 16));
        mx = fmaxf(mx, __shfl_xor(mx, 4, 16));
        mx = fmaxf(mx, __shfl_xor(mx, 8, 16));
        float mnew = fmaxf(mrow[mi][j], mx);
        float alpha = __builtin_amdgcn_exp2f((mrow[mi][j] - mnew) * cf);
        float ps = 0.f;
        #pragma unroll
        for (int ni = 0; ni < 4; ++ni) {
          float p = __builtin_amdgcn_exp2f((sc[mi][ni][j] - mnew) * cf);
          sc[mi][ni][j] = p;
          ps += p;
        }
        ps += __shfl_xor(ps, 1, 16);
        ps += __shfl_xor(ps, 2, 16);
        ps += __shfl_xor(ps, 4, 16);
        ps += __shfl_xor(ps, 8, 16);
        lrow[mi][j] = lrow[mi][j] * alpha + ps;
        mrow[mi][j] = mnew;
        #pragma unroll
        for (int ni = 0; ni < 4; ++ni) o[mi][ni][j] *= alpha;
      }

    // write P (bf16) to per-wave LDS, swizzled for A-frag reads
    #pragma unroll
    for (int mi = 0; mi < 2; ++mi)
      #pragma unroll
      for (int ni = 0; ni < 4; ++ni)
        #pragma unroll
        for (int j = 0; j < 4; ++j) {
          int r = mi * 16 + (lane >> 4) * 4 + j;
          int ccol = ni * 16 + (lane & 15);
          P_lds[wave][r * 64 + (((ccol >> 3) ^ (r & 7)) << 3) + (ccol & 7)] =
              (short)f2bf(sc[mi][ni][j]);
        }
    __syncthreads();

    // PV: o += P(32 x 64) @ V(64 x 64); B-operand from Vt tile rows (=d)
    #pragma unroll
    for (int kk = 0; kk < 2; ++kk) {
      short8 pf[2], vf[4];
      #pragma unroll
      for (int mi = 0; mi < 2; ++mi) {
        int r = mi * 16 + (lane & 15);
        int cs = (kk * 4 + (lane >> 4)) ^ (r & 7);
        pf[mi] = *(const short8*)&P_lds[wave][r * 64 + cs * 8];
      }
      #pragma unroll
      for (int ni = 0; ni < 4; ++ni) {
        int rv = ni * 16 + (lane & 15);
        int cs = (kk * 4 + (lane >> 4)) ^ (rv & 7);
        vf[ni] = *(const short8*)&V_lds[rv * 64 + cs * 8];
      }
      #pragma unroll
      for (int mi = 0; mi < 2; ++mi)
        #pragma unroll
        for (int ni = 0; ni < 4; ++ni)
          o[mi][ni] = mfma_bf16(pf[mi], vf[ni], o[mi][ni]);
    }
  }

  // epilogue: Ob[(b*S + q)*512 + h*64 + d] = o / l
  #pragma unroll
  for (int mi = 0; mi < 2; ++mi)
    #pragma unroll
    for (int j = 0; j < 4; ++j) {
      float inv = 1.f / lrow[mi][j];
      int m = b * S_ + q0 + mi * 16 + (lane >> 4) * 4 + j;
      #pragma unroll
      for (int ni = 0; ni < 4; ++ni) {
        int n = h * 64 + ni * 16 + (lane & 15);
        Ob[(size_t)m * 512 + n] = (short)f2bf(o[mi][ni][j] * inv);
      }
    }
}

// ---------------- launcher ----------------
extern "C" void kernel_launch(void* const* d_in, const int* in_sizes, int n_in,
                              void* d_out, int out_size, void* d_ws, size_t ws_size,
                              hipStream_t stream) {
  const float* x  = (const float*)d_in[0];
  const float* Wq = (const float*)d_in[1];
  const float* bq = (const float*)d_in[2];
  const float* Wk = (const float*)d_in[3];
  const float* bk = (const float*)d_in[4];
  const float* Wv = (const float*)d_in[5];
  const float* bv = (const float*)d_in[6];
  const float* Wo = (const float*)d_in[7];
  const float* bo = (const float*)d_in[8];
  float* out = (float*)d_out;

  short* ws = (short*)d_ws;
  short* xb = ws;                  // 8192*512         = 4,194,304 shorts
  short* Wt = ws + 4194304;        // 4*512*512        = 1,048,576
  short* Qb = ws + 5242880;        // (B,H,S,D)        = 4,194,304
  short* Kb = ws + 9437184;        // (B,H,S,D)        = 4,194,304
  short* Vt = ws + 13631488;       // (B,H,D,S)        = 4,194,304
  short* Ob = ws + 17825792;       // (B*S, 512)       = 4,194,304  (end: 44 MB)

  hipLaunchKernelGGL(sa_convert_x, dim3(2048), dim3(256), 0, stream, x, xb);
  hipLaunchKernelGGL(sa_transpose_w, dim3(16, 16, 4), dim3(32, 8), 0, stream,
                     Wq, Wk, Wv, Wo, Wt);
  hipLaunchKernelGGL(sa_gemm<0>, dim3(64, 4, 3), dim3(256), 0, stream,
                     xb, Wt, bq, bk, bv, Qb, Kb, Vt, (float*)nullptr);
  hipLaunchKernelGGL(sa_attn, dim3(16, 8, 4), dim3(256), 0, stream, Qb, Kb, Vt, Ob);
  hipLaunchKernelGGL(sa_gemm<1>, dim3(64, 4, 1), dim3(256), 0, stream,
                     Ob, Wt, bo, (const float*)nullptr, (const float*)nullptr,
                     (short*)nullptr, (short*)nullptr, (short*)nullptr, out);
}

// Round 2
// 161.301 us; speedup vs baseline: 1.0452x; 1.0452x over previous
//
#include <hip/hip_runtime.h>
#include <stdint.h>

#define B_   4
#define S_   2048
#define IN_  512
#define HID_ 512
#define NH_  8
#define HD_  64
#define M_   (B_*S_)   // 8192

typedef __attribute__((ext_vector_type(8))) short  short8;
typedef __attribute__((ext_vector_type(4))) short  short4v;
typedef __attribute__((ext_vector_type(4))) float  f32x4;
typedef __attribute__((ext_vector_type(8))) __bf16 bf16x8;

// fp32 -> bf16 bits, round-to-nearest-even
__device__ __forceinline__ unsigned short f2bf(float f) {
  union { float f; unsigned u; } v; v.f = f;
  unsigned r = (v.u + 0x7fffu + ((v.u >> 16) & 1u)) >> 16;
  return (unsigned short)r;
}

__device__ __forceinline__ f32x4 mfma_bf16(short8 a, short8 b, f32x4 c) {
  return __builtin_amdgcn_mfma_f32_16x16x32_bf16(
      __builtin_bit_cast(bf16x8, a), __builtin_bit_cast(bf16x8, b), c, 0, 0, 0);
}

// async global->LDS, 16B per lane; dst must be wave-uniform base (lane*16 auto)
__device__ __forceinline__ void gload_lds16(const void* g, void* l) {
  __builtin_amdgcn_global_load_lds(
      (__attribute__((address_space(1))) void*)g,
      (__attribute__((address_space(3))) void*)l, 16, 0, 0);
}

// ---------------- kernel 1: x (fp32) -> xb (bf16) ----------------
__global__ __launch_bounds__(256) void sa_convert_x(const float* __restrict__ x,
                                                    short* __restrict__ xb) {
  int i = (blockIdx.x * 256 + threadIdx.x) * 8;
  const float4* p = (const float4*)&x[i];
  float4 a = p[0], b2 = p[1];
  short8 r;
  r[0] = (short)f2bf(a.x);  r[1] = (short)f2bf(a.y);
  r[2] = (short)f2bf(a.z);  r[3] = (short)f2bf(a.w);
  r[4] = (short)f2bf(b2.x); r[5] = (short)f2bf(b2.y);
  r[6] = (short)f2bf(b2.z); r[7] = (short)f2bf(b2.w);
  *(short8*)&xb[i] = r;
}

// ---------------- kernel 2: W (512x512 fp32) -> Wt (bf16, transposed) ----------------
__global__ __launch_bounds__(256) void sa_transpose_w(const float* __restrict__ Wq,
                                                      const float* __restrict__ Wk,
                                                      const float* __restrict__ Wv,
                                                      const float* __restrict__ Wo,
                                                      short* __restrict__ Wt) {
  __shared__ float tile[32][33];
  const int z = blockIdx.z;
  const float* src = (z == 0) ? Wq : (z == 1) ? Wk : (z == 2) ? Wv : Wo;
  const int k0 = blockIdx.y * 32, n0 = blockIdx.x * 32;
  const int tx = threadIdx.x, ty = threadIdx.y;   // (32, 8)
  #pragma unroll
  for (int i = 0; i < 32; i += 8)
    tile[ty + i][tx] = src[(size_t)(k0 + ty + i) * 512 + n0 + tx];
  __syncthreads();
  short* dst = Wt + (size_t)z * 262144;
  #pragma unroll
  for (int i = 0; i < 32; i += 8)
    dst[(size_t)(n0 + ty + i) * 512 + k0 + tx] = (short)f2bf(tile[tx][ty + i]);
}

// ---------------- GEMM: C(8192x512) = A(8192x512,bf16) @ W(512x512) + bias ----------------
template <int MODE>
__global__ __launch_bounds__(256) void sa_gemm(const short* __restrict__ Abuf,
                                               const short* __restrict__ Wt,
                                               const float* __restrict__ bias0,
                                               const float* __restrict__ bias1,
                                               const float* __restrict__ bias2,
                                               short* __restrict__ Qb,
                                               short* __restrict__ Kb,
                                               short* __restrict__ Vt,
                                               float* __restrict__ outp) {
  __shared__ __align__(16) short A_lds[128 * 64];
  __shared__ __align__(16) short B_lds[128 * 64];
  const int tid = threadIdx.x, lane = tid & 63, wave = tid >> 6;
  const int row0 = blockIdx.x * 128, col0 = blockIdx.y * 128;
  const int z = (MODE == 0) ? blockIdx.z : 3;
  const short* Bsrc = Wt + (size_t)z * 262144;   // [512 n][512 k]
  const int wr = wave >> 1, wc = wave & 1;

  f32x4 acc[4][4];
  const f32x4 zf = {0.f, 0.f, 0.f, 0.f};
  #pragma unroll
  for (int mi = 0; mi < 4; ++mi)
    #pragma unroll
    for (int ni = 0; ni < 4; ++ni) acc[mi][ni] = zf;

  for (int k0 = 0; k0 < 512; k0 += 64) {
    __syncthreads();
    #pragma unroll
    for (int j = 0; j < 4; ++j) {
      int chunk = j * 256 + wave * 64 + lane;   // 1024 chunks of 8 bf16
      int row = chunk >> 3;
      int cc = (chunk & 7) ^ (row & 7);
      gload_lds16(Abuf + (size_t)(row0 + row) * 512 + k0 + cc * 8,
                  &A_lds[(j * 256 + wave * 64) * 8]);
      gload_lds16(Bsrc + (size_t)(col0 + row) * 512 + k0 + cc * 8,
                  &B_lds[(j * 256 + wave * 64) * 8]);
    }
    __syncthreads();
    #pragma unroll
    for (int kk = 0; kk < 2; ++kk) {
      short8 af[4], bf[4];
      #pragma unroll
      for (int mi = 0; mi < 4; ++mi) {
        int r = wr * 64 + mi * 16 + (lane & 15);
        int cs = (kk * 4 + (lane >> 4)) ^ (r & 7);
        af[mi] = *(const short8*)&A_lds[r * 64 + cs * 8];
      }
      #pragma unroll
      for (int ni = 0; ni < 4; ++ni) {
        int r = wc * 64 + ni * 16 + (lane & 15);
        int cs = (kk * 4 + (lane >> 4)) ^ (r & 7);
        bf[ni] = *(const short8*)&B_lds[r * 64 + cs * 8];
      }
      #pragma unroll
      for (int mi = 0; mi < 4; ++mi)
        #pragma unroll
        for (int ni = 0; ni < 4; ++ni)
          acc[mi][ni] = mfma_bf16(af[mi], bf[ni], acc[mi][ni]);
    }
  }

  if (MODE == 0) {
    const float* bias = (z == 0) ? bias0 : (z == 1) ? bias1 : bias2;
    #pragma unroll
    for (int ni = 0; ni < 4; ++ni) {
      int n = col0 + wc * 64 + ni * 16 + (lane & 15);
      float bsv = bias[n];
      int hh = n >> 6, dd = n & 63;
      #pragma unroll
      for (int mi = 0; mi < 4; ++mi) {
        int rg = row0 + wr * 64 + mi * 16 + ((lane >> 4) << 2);
        int bb = rg >> 11, ss = rg & 2047;
        if (z <= 1) {
          short* dst = (z == 0) ? Qb : Kb;
          size_t base = ((size_t)(bb * NH_ + hh) << 17);
          #pragma unroll
          for (int j = 0; j < 4; ++j)
            dst[base + (size_t)(ss + j) * 64 + dd] = (short)f2bf(acc[mi][ni][j] + bsv);
        } else {
          size_t base = ((size_t)(bb * NH_ + hh) << 17) + (size_t)dd * 2048 + ss;
          short4v pk;
          #pragma unroll
          for (int j = 0; j < 4; ++j) pk[j] = (short)f2bf(acc[mi][ni][j] + bsv);
          *(short4v*)&Vt[base] = pk;
        }
      }
    }
  } else {
    #pragma unroll
    for (int ni = 0; ni < 4; ++ni) {
      int n = col0 + wc * 64 + ni * 16 + (lane & 15);
      float bsv = bias0[n];
      #pragma unroll
      for (int mi = 0; mi < 4; ++mi) {
        int rg = row0 + wr * 64 + mi * 16 + ((lane >> 4) << 2);
        #pragma unroll
        for (int j = 0; j < 4; ++j)
          outp[(size_t)(rg + j) * 512 + n] = acc[mi][ni][j] + bsv;
      }
    }
  }
}

// ---------------- kernel 4: flash attention ----------------
// grid (S/128, H, B), 512 threads (8 waves); wave owns 16 q-rows. KBLK=128.
__global__ __launch_bounds__(512, 4) void sa_attn(const short* __restrict__ Qb,
                                                  const short* __restrict__ Kb,
                                                  const short* __restrict__ Vt,
                                                  short* __restrict__ Ob) {
  __shared__ __align__(16) short K_lds[128 * 64];    // 16 KB, [kpos][d]
  __shared__ __align__(16) short V_lds[64 * 128];    // 16 KB, [d][kpos]
  __shared__ __align__(16) short P_lds[8][16 * 128]; // 32 KB, per-wave [q][kpos]
  const int tid = threadIdx.x, lane = tid & 63, wave = tid >> 6;
  const int h = blockIdx.y, b = blockIdx.z;
  const size_t bh = ((size_t)(b * NH_ + h)) << 17;
  const int q0 = blockIdx.x * 128 + wave * 16;

  // Q fragments (A-operand): row=q0+(lane&15), k=kk*32+(lane>>4)*8
  short8 qf[2];
  #pragma unroll
  for (int kk = 0; kk < 2; ++kk)
    qf[kk] = *(const short8*)&Qb[bh + (size_t)(q0 + (lane & 15)) * 64 +
                                 kk * 32 + ((lane >> 4) * 8)];

  f32x4 o[4];
  float mrow[4], lrow[4];
  const f32x4 zf = {0.f, 0.f, 0.f, 0.f};
  #pragma unroll
  for (int ni = 0; ni < 4; ++ni) o[ni] = zf;
  #pragma unroll
  for (int j = 0; j < 4; ++j) { mrow[j] = -3.0e38f; lrow[j] = 0.f; }
  const float cf = 0.18033688011112042f;   // log2(e)/8

  for (int k0 = 0; k0 < S_; k0 += 128) {
    __syncthreads();
    // stage K tile [128][64] and V tile [64][128], source pre-swizzled (rule #21)
    #pragma unroll
    for (int j = 0; j < 2; ++j) {
      int chunk = j * 512 + tid;          // 1024 chunks of 8 bf16 each
      int kr = chunk >> 3, kc = (chunk & 7) ^ (kr & 7);
      gload_lds16(&Kb[bh + (size_t)(k0 + kr) * 64 + kc * 8],
                  &K_lds[(j * 512 + wave * 64) * 8]);
      int vr = chunk >> 4, vc = (chunk & 15) ^ (vr & 15);
      gload_lds16(&Vt[bh + (size_t)vr * 2048 + k0 + vc * 8],
                  &V_lds[(j * 512 + wave * 64) * 8]);
    }
    __syncthreads();

    // QK^T: sc[ni] = 16q x 16k tile at k-cols ni*16
    f32x4 sc[8];
    #pragma unroll
    for (int ni = 0; ni < 8; ++ni) sc[ni] = zf;
    #pragma unroll
    for (int kk = 0; kk < 2; ++kk)
      #pragma unroll
      for (int ni = 0; ni < 8; ++ni) {
        int r = ni * 16 + (lane & 15);
        int cs = (kk * 4 + (lane >> 4)) ^ (r & 7);
        short8 kfv = *(const short8*)&K_lds[r * 64 + cs * 8];
        sc[ni] = mfma_bf16(qf[kk], kfv, sc[ni]);
      }

    // online softmax; lane's rows r = (lane>>4)*4 + j
    float mnew[4], ps[4];
    int loc = 1;
    #pragma unroll
    for (int j = 0; j < 4; ++j) {
      float mx = fmaxf(fmaxf(fmaxf(sc[0][j], sc[1][j]), fmaxf(sc[2][j], sc[3][j])),
                       fmaxf(fmaxf(sc[4][j], sc[5][j]), fmaxf(sc[6][j], sc[7][j])));
      mx = fmaxf(mx, __shfl_xor(mx, 1, 16));
      mx = fmaxf(mx, __shfl_xor(mx, 2, 16));
      mx = fmaxf(mx, __shfl_xor(mx, 4, 16));
      mx = fmaxf(mx, __shfl_xor(mx, 8, 16));
      mnew[j] = fmaxf(mrow[j], mx);
      loc &= (mnew[j] == mrow[j]);
    }
    const bool nores = __all(loc);
    #pragma unroll
    for (int j = 0; j < 4; ++j) {
      float s = 0.f;
      #pragma unroll
      for (int ni = 0; ni < 8; ++ni) {
        float p = __builtin_amdgcn_exp2f((sc[ni][j] - mnew[j]) * cf);
        sc[ni][j] = p;
        s += p;
      }
      s += __shfl_xor(s, 1, 16);
      s += __shfl_xor(s, 2, 16);
      s += __shfl_xor(s, 4, 16);
      s += __shfl_xor(s, 8, 16);
      ps[j] = s;
    }
    if (nores) {
      #pragma unroll
      for (int j = 0; j < 4; ++j) lrow[j] += ps[j];
    } else {
      #pragma unroll
      for (int j = 0; j < 4; ++j) {
        float al = __builtin_amdgcn_exp2f((mrow[j] - mnew[j]) * cf);
        lrow[j] = lrow[j] * al + ps[j];
        mrow[j] = mnew[j];
        #pragma unroll
        for (int ni = 0; ni < 4; ++ni) o[ni][j] *= al;
      }
    }

    // write P (bf16) to per-wave LDS [16][128], swizzled
    #pragma unroll
    for (int ni = 0; ni < 8; ++ni)
      #pragma unroll
      for (int j = 0; j < 4; ++j) {
        int r = ((lane >> 4) << 2) + j;
        int col = ni * 16 + (lane & 15);
        int cs = (col >> 3) ^ r;
        P_lds[wave][r * 128 + (cs << 3) + (col & 7)] = (short)f2bf(sc[ni][j]);
      }

    // PV: o += P(16 x 128) @ V(128 x 64); in-wave LDS RAW is in-order
    #pragma unroll
    for (int kk = 0; kk < 4; ++kk) {
      int pr = lane & 15;
      int pcs = (kk * 4 + (lane >> 4)) ^ pr;
      short8 pf = *(const short8*)&P_lds[wave][pr * 128 + pcs * 8];
      #pragma unroll
      for (int ni = 0; ni < 4; ++ni) {
        int rv = ni * 16 + (lane & 15);
        int vcs = (kk * 4 + (lane >> 4)) ^ (rv & 15);
        short8 vf = *(const short8*)&V_lds[rv * 128 + vcs * 8];
        o[ni] = mfma_bf16(pf, vf, o[ni]);
      }
    }
  }

  // epilogue: Ob[(b*S + q)*512 + h*64 + d] = o / l
  #pragma unroll
  for (int j = 0; j < 4; ++j) {
    float inv = 1.f / lrow[j];
    int m = b * S_ + q0 + ((lane >> 4) << 2) + j;
    #pragma unroll
    for (int ni = 0; ni < 4; ++ni) {
      int n = h * 64 + ni * 16 + (lane & 15);
      Ob[(size_t)m * 512 + n] = (short)f2bf(o[ni][j] * inv);
    }
  }
}

// ---------------- launcher ----------------
extern "C" void kernel_launch(void* const* d_in, const int* in_sizes, int n_in,
                              void* d_out, int out_size, void* d_ws, size_t ws_size,
                              hipStream_t stream) {
  const float* x  = (const float*)d_in[0];
  const float* Wq = (const float*)d_in[1];
  const float* bq = (const float*)d_in[2];
  const float* Wk = (const float*)d_in[3];
  const float* bk = (const float*)d_in[4];
  const float* Wv = (const float*)d_in[5];
  const float* bv = (const float*)d_in[6];
  const float* Wo = (const float*)d_in[7];
  const float* bo = (const float*)d_in[8];
  float* out = (float*)d_out;

  short* ws = (short*)d_ws;
  short* xb = ws;                  // 8192*512         = 4,194,304 shorts
  short* Wt = ws + 4194304;        // 4*512*512        = 1,048,576
  short* Qb = ws + 5242880;        // (B,H,S,D)        = 4,194,304
  short* Kb = ws + 9437184;        // (B,H,S,D)        = 4,194,304
  short* Vt = ws + 13631488;       // (B,H,D,S)        = 4,194,304
  short* Ob = ws + 17825792;       // (B*S, 512)       = 4,194,304  (end: 44 MB)

  hipLaunchKernelGGL(sa_convert_x, dim3(2048), dim3(256), 0, stream, x, xb);
  hipLaunchKernelGGL(sa_transpose_w, dim3(16, 16, 4), dim3(32, 8), 0, stream,
                     Wq, Wk, Wv, Wo, Wt);
  hipLaunchKernelGGL(sa_gemm<0>, dim3(64, 4, 3), dim3(256), 0, stream,
                     xb, Wt, bq, bk, bv, Qb, Kb, Vt, (float*)nullptr);
  hipLaunchKernelGGL(sa_attn, dim3(16, 8, 4), dim3(512), 0, stream, Qb, Kb, Vt, Ob);
  hipLaunchKernelGGL(sa_gemm<1>, dim3(64, 4, 1), dim3(256), 0, stream,
                     Ob, Wt, bo, (const float*)nullptr, (const float*)nullptr,
                     (short*)nullptr, (short*)nullptr, (short*)nullptr, out);
}

// Round 3
// 130.533 us; speedup vs baseline: 1.2916x; 1.2357x over previous
//
#include <hip/hip_runtime.h>
#include <stdint.h>

#define B_   4
#define S_   2048
#define IN_  512
#define HID_ 512
#define NH_  8
#define HD_  64
#define M_   (B_*S_)   // 8192

typedef __attribute__((ext_vector_type(8)))  short  short8;
typedef __attribute__((ext_vector_type(4)))  short  short4v;
typedef __attribute__((ext_vector_type(4)))  float  f32x4;
typedef __attribute__((ext_vector_type(16))) float  f32x16;
typedef __attribute__((ext_vector_type(8)))  __bf16 bf16x8;
typedef __attribute__((ext_vector_type(2)))  __bf16 bf16x2;
typedef __attribute__((ext_vector_type(4)))  unsigned int u32x4;

// fp32 -> bf16 bits, round-to-nearest-even
__device__ __forceinline__ unsigned short f2bf(float f) {
  union { float f; unsigned u; } v; v.f = f;
  unsigned r = (v.u + 0x7fffu + ((v.u >> 16) & 1u)) >> 16;
  return (unsigned short)r;
}

// pack 2 f32 -> u32 of 2 bf16 (compiler emits v_cvt_pk_bf16_f32)
__device__ __forceinline__ unsigned int packbf(float a, float b) {
  bf16x2 t; t[0] = (__bf16)a; t[1] = (__bf16)b;
  return __builtin_bit_cast(unsigned int, t);
}

__device__ __forceinline__ f32x4 mfma_bf16(short8 a, short8 b, f32x4 c) {
  return __builtin_amdgcn_mfma_f32_16x16x32_bf16(
      __builtin_bit_cast(bf16x8, a), __builtin_bit_cast(bf16x8, b), c, 0, 0, 0);
}

__device__ __forceinline__ f32x16 mfma32(short8 a, short8 b, f32x16 c) {
  return __builtin_amdgcn_mfma_f32_32x32x16_bf16(
      __builtin_bit_cast(bf16x8, a), __builtin_bit_cast(bf16x8, b), c, 0, 0, 0);
}

// async global->LDS, 16B per lane; dst must be wave-uniform base (lane*16 auto)
__device__ __forceinline__ void gload_lds16(const void* g, void* l) {
  __builtin_amdgcn_global_load_lds(
      (__attribute__((address_space(1))) void*)g,
      (__attribute__((address_space(3))) void*)l, 16, 0, 0);
}

// ---------------- kernel 1: x (fp32) -> xb (bf16) ----------------
__global__ __launch_bounds__(256) void sa_convert_x(const float* __restrict__ x,
                                                    short* __restrict__ xb) {
  int i = (blockIdx.x * 256 + threadIdx.x) * 8;
  const float4* p = (const float4*)&x[i];
  float4 a = p[0], b2 = p[1];
  short8 r;
  r[0] = (short)f2bf(a.x);  r[1] = (short)f2bf(a.y);
  r[2] = (short)f2bf(a.z);  r[3] = (short)f2bf(a.w);
  r[4] = (short)f2bf(b2.x); r[5] = (short)f2bf(b2.y);
  r[6] = (short)f2bf(b2.z); r[7] = (short)f2bf(b2.w);
  *(short8*)&xb[i] = r;
}

// ---------------- kernel 2: W (512x512 fp32) -> Wt (bf16, transposed) ----------------
__global__ __launch_bounds__(256) void sa_transpose_w(const float* __restrict__ Wq,
                                                      const float* __restrict__ Wk,
                                                      const float* __restrict__ Wv,
                                                      const float* __restrict__ Wo,
                                                      short* __restrict__ Wt) {
  __shared__ float tile[32][33];
  const int z = blockIdx.z;
  const float* src = (z == 0) ? Wq : (z == 1) ? Wk : (z == 2) ? Wv : Wo;
  const int k0 = blockIdx.y * 32, n0 = blockIdx.x * 32;
  const int tx = threadIdx.x, ty = threadIdx.y;   // (32, 8)
  #pragma unroll
  for (int i = 0; i < 32; i += 8)
    tile[ty + i][tx] = src[(size_t)(k0 + ty + i) * 512 + n0 + tx];
  __syncthreads();
  short* dst = Wt + (size_t)z * 262144;
  #pragma unroll
  for (int i = 0; i < 32; i += 8)
    dst[(size_t)(n0 + ty + i) * 512 + k0 + tx] = (short)f2bf(tile[tx][ty + i]);
}

// ---------------- GEMM: C(8192x512) = A(8192x512,bf16) @ W(512x512) + bias ----------------
template <int MODE>
__global__ __launch_bounds__(256) void sa_gemm(const short* __restrict__ Abuf,
                                               const short* __restrict__ Wt,
                                               const float* __restrict__ bias0,
                                               const float* __restrict__ bias1,
                                               const float* __restrict__ bias2,
                                               short* __restrict__ Qb,
                                               short* __restrict__ Kb,
                                               short* __restrict__ Vt,
                                               float* __restrict__ outp) {
  __shared__ __align__(16) short A_lds[128 * 64];
  __shared__ __align__(16) short B_lds[128 * 64];
  const int tid = threadIdx.x, lane = tid & 63, wave = tid >> 6;
  const int row0 = blockIdx.x * 128, col0 = blockIdx.y * 128;
  const int z = (MODE == 0) ? blockIdx.z : 3;
  const short* Bsrc = Wt + (size_t)z * 262144;   // [512 n][512 k]
  const int wr = wave >> 1, wc = wave & 1;

  f32x4 acc[4][4];
  const f32x4 zf = {0.f, 0.f, 0.f, 0.f};
  #pragma unroll
  for (int mi = 0; mi < 4; ++mi)
    #pragma unroll
    for (int ni = 0; ni < 4; ++ni) acc[mi][ni] = zf;

  for (int k0 = 0; k0 < 512; k0 += 64) {
    __syncthreads();
    #pragma unroll
    for (int j = 0; j < 4; ++j) {
      int chunk = j * 256 + wave * 64 + lane;   // 1024 chunks of 8 bf16
      int row = chunk >> 3;
      int cc = (chunk & 7) ^ (row & 7);
      gload_lds16(Abuf + (size_t)(row0 + row) * 512 + k0 + cc * 8,
                  &A_lds[(j * 256 + wave * 64) * 8]);
      gload_lds16(Bsrc + (size_t)(col0 + row) * 512 + k0 + cc * 8,
                  &B_lds[(j * 256 + wave * 64) * 8]);
    }
    __syncthreads();
    #pragma unroll
    for (int kk = 0; kk < 2; ++kk) {
      short8 af[4], bf[4];
      #pragma unroll
      for (int mi = 0; mi < 4; ++mi) {
        int r = wr * 64 + mi * 16 + (lane & 15);
        int cs = (kk * 4 + (lane >> 4)) ^ (r & 7);
        af[mi] = *(const short8*)&A_lds[r * 64 + cs * 8];
      }
      #pragma unroll
      for (int ni = 0; ni < 4; ++ni) {
        int r = wc * 64 + ni * 16 + (lane & 15);
        int cs = (kk * 4 + (lane >> 4)) ^ (r & 7);
        bf[ni] = *(const short8*)&B_lds[r * 64 + cs * 8];
      }
      #pragma unroll
      for (int mi = 0; mi < 4; ++mi)
        #pragma unroll
        for (int ni = 0; ni < 4; ++ni)
          acc[mi][ni] = mfma_bf16(af[mi], bf[ni], acc[mi][ni]);
    }
  }

  if (MODE == 0) {
    const float* bias = (z == 0) ? bias0 : (z == 1) ? bias1 : bias2;
    #pragma unroll
    for (int ni = 0; ni < 4; ++ni) {
      int n = col0 + wc * 64 + ni * 16 + (lane & 15);
      float bsv = bias[n];
      int hh = n >> 6, dd = n & 63;
      #pragma unroll
      for (int mi = 0; mi < 4; ++mi) {
        int rg = row0 + wr * 64 + mi * 16 + ((lane >> 4) << 2);
        int bb = rg >> 11, ss = rg & 2047;
        if (z <= 1) {
          short* dst = (z == 0) ? Qb : Kb;
          size_t base = ((size_t)(bb * NH_ + hh) << 17);
          #pragma unroll
          for (int j = 0; j < 4; ++j)
            dst[base + (size_t)(ss + j) * 64 + dd] = (short)f2bf(acc[mi][ni][j] + bsv);
        } else {
          size_t base = ((size_t)(bb * NH_ + hh) << 17) + (size_t)dd * 2048 + ss;
          short4v pk;
          #pragma unroll
          for (int j = 0; j < 4; ++j) pk[j] = (short)f2bf(acc[mi][ni][j] + bsv);
          *(short4v*)&Vt[base] = pk;
        }
      }
    }
  } else {
    #pragma unroll
    for (int ni = 0; ni < 4; ++ni) {
      int n = col0 + wc * 64 + ni * 16 + (lane & 15);
      float bsv = bias0[n];
      #pragma unroll
      for (int mi = 0; mi < 4; ++mi) {
        int rg = row0 + wr * 64 + mi * 16 + ((lane >> 4) << 2);
        #pragma unroll
        for (int j = 0; j < 4; ++j)
          outp[(size_t)(rg + j) * 512 + n] = acc[mi][ni][j] + bsv;
      }
    }
  }
}

// ---------------- kernel 4: flash attention (32x32 MFMA, swapped QK^T) ----------------
// grid (S/128, H, B), 256 threads (4 waves); wave owns 32 q-rows. KBLK=64, dbuf LDS.
__global__ __launch_bounds__(256) void sa_attn(const short* __restrict__ Qb,
                                               const short* __restrict__ Kb,
                                               const short* __restrict__ Vt,
                                               short* __restrict__ Ob) {
  __shared__ __align__(16) short K_lds[2][64 * 64];   // [kpos][d], 8 KB each
  __shared__ __align__(16) short V_lds[2][64 * 64];   // [d][kpos], 8 KB each
  const int tid = threadIdx.x, lane = tid & 63, wave = tid >> 6;
  const int hb = blockIdx.y, b = blockIdx.z;
  const size_t bh = ((size_t)(b * NH_ + hb)) << 17;
  const int q0w = blockIdx.x * 128 + wave * 32;
  const int l31 = lane & 31, hh = lane >> 5;

  // Q frags (B-operand): q = q0w + l31, d = c*16 + hh*8 + {0..7}
  short8 qf[4];
  #pragma unroll
  for (int c = 0; c < 4; ++c)
    qf[c] = *(const short8*)&Qb[bh + (size_t)(q0w + l31) * 64 + c * 16 + hh * 8];

  f32x16 o0 = {}, o1 = {};
  float mrow = -3.0e38f, lrow = 0.f;
  const float cf = 0.18033688011112042f;   // log2(e)/8
  const int base32 = lane & 32;

  // stage K tile [64][64] + V tile [64][64] for step t into buffer `sbuf`
  auto STAGE = [&](int sbuf, int t) {
    const int k0 = t * 64;
    #pragma unroll
    for (int j = 0; j < 2; ++j) {
      int chunk = j * 256 + tid;               // 512 granules of 16B each
      int row = chunk >> 3, g = (chunk & 7) ^ (row & 7);
      gload_lds16(&Kb[bh + (size_t)(k0 + row) * 64 + g * 8],
                  &K_lds[sbuf][(j * 256 + wave * 64) * 8]);
      gload_lds16(&Vt[bh + (size_t)row * 2048 + k0 + g * 8],
                  &V_lds[sbuf][(j * 256 + wave * 64) * 8]);
    }
  };

  STAGE(0, 0);
  __syncthreads();

  for (int t = 0; t < S_ / 64; ++t) {
    const int buf = t & 1;
    if (t + 1 < S_ / 64) STAGE(buf ^ 1, t + 1);   // prefetch overlaps compute

    // ---- QK^T (swapped): sc[kt] lane layout: q = l31, kpos = kt*32+(reg&3)+8*(reg>>2)+4*hh
    f32x16 sc0 = {}, sc1 = {};
    #pragma unroll
    for (int c = 0; c < 4; ++c) {
      int sw = ((2 * c + hh) ^ (l31 & 7)) * 8;
      short8 kf0 = *(const short8*)&K_lds[buf][l31 * 64 + sw];
      short8 kf1 = *(const short8*)&K_lds[buf][(32 + l31) * 64 + sw];
      sc0 = mfma32(kf0, qf[c], sc0);
      sc1 = mfma32(kf1, qf[c], sc1);
    }

    // ---- softmax: in-lane over 32 values + one cross-half swap
    float mx = fmaxf(sc0[0], sc1[0]);
    #pragma unroll
    for (int r = 1; r < 16; ++r) mx = fmaxf(mx, fmaxf(sc0[r], sc1[r]));
    mx = fmaxf(mx, __shfl_xor(mx, 32));
    float mnew = fmaxf(mrow, mx);
    bool nores = __all(mnew == mrow);

    float s = 0.f;
    #pragma unroll
    for (int r = 0; r < 16; ++r) {
      float p0 = __builtin_amdgcn_exp2f((sc0[r] - mnew) * cf);
      float p1 = __builtin_amdgcn_exp2f((sc1[r] - mnew) * cf);
      sc0[r] = p0; sc1[r] = p1;
      s += p0 + p1;
    }
    s += __shfl_xor(s, 32);

    if (nores) {
      lrow += s;
    } else {
      float al = __builtin_amdgcn_exp2f((mrow - mnew) * cf);
      mrow = mnew;
      lrow = lrow * al + s;
      #pragma unroll
      for (int r = 0; r < 16; ++r) {
        int qr = (r & 3) + 8 * (r >> 2) + 4 * hh;
        float ar = __shfl(al, base32 + qr);
        o0[r] *= ar; o1[r] *= ar;
      }
    }

    // ---- pack P to bf16 words; W[i]: k = (i>>3)*32 + 8*((i>>1)&3) + 4*hh + 2*(i&1) + {0,1}
    unsigned int W[16], Sx[16];
    #pragma unroll
    for (int m = 0; m < 4; ++m) {
      W[2 * m]     = packbf(sc0[4 * m],     sc0[4 * m + 1]);
      W[2 * m + 1] = packbf(sc0[4 * m + 2], sc0[4 * m + 3]);
      W[8 + 2 * m]     = packbf(sc1[4 * m],     sc1[4 * m + 1]);
      W[8 + 2 * m + 1] = packbf(sc1[4 * m + 2], sc1[4 * m + 3]);
    }
    #pragma unroll
    for (int i = 0; i < 16; ++i)
      Sx[i] = (unsigned int)__shfl_xor((int)W[i], 32);

    // ---- PV: o += P(32q x 64k) @ V(64k x 64d)
    #pragma unroll
    for (int kc = 0; kc < 4; ++kc) {
      // A-frag(kc): k = kc*16 + hh*8 + {0..7}; halves from own/partner words
      unsigned int f0 = hh ? Sx[4 * kc + 2] : W[4 * kc];
      unsigned int f1 = hh ? Sx[4 * kc + 3] : W[4 * kc + 1];
      unsigned int f2 = hh ? W[4 * kc + 2]  : Sx[4 * kc];
      unsigned int f3 = hh ? W[4 * kc + 3]  : Sx[4 * kc + 1];
      u32x4 paw = {f0, f1, f2, f3};
      short8 pa = __builtin_bit_cast(short8, paw);
      int sw = ((2 * kc + hh) ^ (l31 & 7)) * 8;
      short8 vf0 = *(const short8*)&V_lds[buf][l31 * 64 + sw];
      short8 vf1 = *(const short8*)&V_lds[buf][(32 + l31) * 64 + sw];
      o0 = mfma32(pa, vf0, o0);
      o1 = mfma32(pa, vf1, o1);
    }
    __syncthreads();   // drains prefetch vmcnt + protects buf reuse
  }

  // ---- epilogue: Ob[(b*S + q)*512 + hb*64 + d] = o / l
  float rli = 1.f / lrow;
  #pragma unroll
  for (int r = 0; r < 16; ++r) {
    int qr = (r & 3) + 8 * (r >> 2) + 4 * hh;
    float li = __shfl(rli, base32 + qr);
    size_t rowb = ((size_t)(b * S_ + q0w + qr)) * 512 + hb * 64;
    Ob[rowb + l31]      = (short)f2bf(o0[r] * li);
    Ob[rowb + 32 + l31] = (short)f2bf(o1[r] * li);
  }
}

// ---------------- launcher ----------------
extern "C" void kernel_launch(void* const* d_in, const int* in_sizes, int n_in,
                              void* d_out, int out_size, void* d_ws, size_t ws_size,
                              hipStream_t stream) {
  const float* x  = (const float*)d_in[0];
  const float* Wq = (const float*)d_in[1];
  const float* bq = (const float*)d_in[2];
  const float* Wk = (const float*)d_in[3];
  const float* bk = (const float*)d_in[4];
  const float* Wv = (const float*)d_in[5];
  const float* bv = (const float*)d_in[6];
  const float* Wo = (const float*)d_in[7];
  const float* bo = (const float*)d_in[8];
  float* out = (float*)d_out;

  short* ws = (short*)d_ws;
  short* xb = ws;                  // 8192*512         = 4,194,304 shorts
  short* Wt = ws + 4194304;        // 4*512*512        = 1,048,576
  short* Qb = ws + 5242880;        // (B,H,S,D)        = 4,194,304
  short* Kb = ws + 9437184;        // (B,H,S,D)        = 4,194,304
  short* Vt = ws + 13631488;       // (B,H,D,S)        = 4,194,304
  short* Ob = ws + 17825792;       // (B*S, 512)       = 4,194,304  (end: 44 MB)

  hipLaunchKernelGGL(sa_convert_x, dim3(2048), dim3(256), 0, stream, x, xb);
  hipLaunchKernelGGL(sa_transpose_w, dim3(16, 16, 4), dim3(32, 8), 0, stream,
                     Wq, Wk, Wv, Wo, Wt);
  hipLaunchKernelGGL(sa_gemm<0>, dim3(64, 4, 3), dim3(256), 0, stream,
                     xb, Wt, bq, bk, bv, Qb, Kb, Vt, (float*)nullptr);
  hipLaunchKernelGGL(sa_attn, dim3(16, 8, 4), dim3(256), 0, stream, Qb, Kb, Vt, Ob);
  hipLaunchKernelGGL(sa_gemm<1>, dim3(64, 4, 1), dim3(256), 0, stream,
                     Ob, Wt, bo, (const float*)nullptr, (const float*)nullptr,
                     (short*)nullptr, (short*)nullptr, (short*)nullptr, out);
}

// Round 4
// 122.547 us; speedup vs baseline: 1.3757x; 1.0652x over previous
//
#include <hip/hip_runtime.h>
#include <stdint.h>

#define B_   4
#define S_   2048
#define IN_  512
#define HID_ 512
#define NH_  8
#define HD_  64
#define M_   (B_*S_)   // 8192

typedef __attribute__((ext_vector_type(8)))  short  short8;
typedef __attribute__((ext_vector_type(4)))  short  short4v;
typedef __attribute__((ext_vector_type(4)))  float  f32x4;
typedef __attribute__((ext_vector_type(16))) float  f32x16;
typedef __attribute__((ext_vector_type(8)))  __bf16 bf16x8;
typedef __attribute__((ext_vector_type(2)))  __bf16 bf16x2;
typedef __attribute__((ext_vector_type(4)))  unsigned int u32x4;

// fp32 -> bf16 bits, round-to-nearest-even
__device__ __forceinline__ unsigned short f2bf(float f) {
  union { float f; unsigned u; } v; v.f = f;
  unsigned r = (v.u + 0x7fffu + ((v.u >> 16) & 1u)) >> 16;
  return (unsigned short)r;
}

// pack 2 f32 -> u32 of 2 bf16 (v_cvt_pk_bf16_f32)
__device__ __forceinline__ unsigned int packbf(float a, float b) {
  bf16x2 t; t[0] = (__bf16)a; t[1] = (__bf16)b;
  return __builtin_bit_cast(unsigned int, t);
}

__device__ __forceinline__ f32x4 mfma_bf16(short8 a, short8 b, f32x4 c) {
  return __builtin_amdgcn_mfma_f32_16x16x32_bf16(
      __builtin_bit_cast(bf16x8, a), __builtin_bit_cast(bf16x8, b), c, 0, 0, 0);
}

__device__ __forceinline__ f32x16 mfma32(short8 a, short8 b, f32x16 c) {
  return __builtin_amdgcn_mfma_f32_32x32x16_bf16(
      __builtin_bit_cast(bf16x8, a), __builtin_bit_cast(bf16x8, b), c, 0, 0, 0);
}

// async global->LDS, 16B per lane; dst wave-uniform base (+lane*16 implicit)
__device__ __forceinline__ void gload_lds16(const void* g, void* l) {
  __builtin_amdgcn_global_load_lds(
      (__attribute__((address_space(1))) void*)g,
      (__attribute__((address_space(3))) void*)l, 16, 0, 0);
}

// ---------------- kernel 1: x (fp32) -> xb (bf16) ----------------
__global__ __launch_bounds__(256) void sa_convert_x(const float* __restrict__ x,
                                                    short* __restrict__ xb) {
  int i = (blockIdx.x * 256 + threadIdx.x) * 8;
  const float4* p = (const float4*)&x[i];
  float4 a = p[0], b2 = p[1];
  short8 r;
  r[0] = (short)f2bf(a.x);  r[1] = (short)f2bf(a.y);
  r[2] = (short)f2bf(a.z);  r[3] = (short)f2bf(a.w);
  r[4] = (short)f2bf(b2.x); r[5] = (short)f2bf(b2.y);
  r[6] = (short)f2bf(b2.z); r[7] = (short)f2bf(b2.w);
  *(short8*)&xb[i] = r;
}

// ---------------- kernel 2: W (512x512 fp32) -> Wt (bf16, transposed) ----------------
__global__ __launch_bounds__(256) void sa_transpose_w(const float* __restrict__ Wq,
                                                      const float* __restrict__ Wk,
                                                      const float* __restrict__ Wv,
                                                      const float* __restrict__ Wo,
                                                      short* __restrict__ Wt) {
  __shared__ float tile[32][33];
  const int z = blockIdx.z;
  const float* src = (z == 0) ? Wq : (z == 1) ? Wk : (z == 2) ? Wv : Wo;
  const int k0 = blockIdx.y * 32, n0 = blockIdx.x * 32;
  const int tx = threadIdx.x, ty = threadIdx.y;   // (32, 8)
  #pragma unroll
  for (int i = 0; i < 32; i += 8)
    tile[ty + i][tx] = src[(size_t)(k0 + ty + i) * 512 + n0 + tx];
  __syncthreads();
  short* dst = Wt + (size_t)z * 262144;
  #pragma unroll
  for (int i = 0; i < 32; i += 8)
    dst[(size_t)(n0 + ty + i) * 512 + k0 + tx] = (short)f2bf(tile[tx][ty + i]);
}

// ---------------- GEMM: C(8192x512) = A(8192x512,bf16) @ W(512x512) + bias ----------------
// MODE 0: z in {0,1,2} -> Q (row-major BHSD), K (fragment-order), V (fragment-order)
// MODE 1: z=3 (Wo) -> fp32 d_out with bo
template <int MODE>
__global__ __launch_bounds__(256) void sa_gemm(const short* __restrict__ Abuf,
                                               const short* __restrict__ Wt,
                                               const float* __restrict__ bias0,
                                               const float* __restrict__ bias1,
                                               const float* __restrict__ bias2,
                                               short* __restrict__ Qb,
                                               short* __restrict__ Kb2,
                                               short* __restrict__ Vb2,
                                               float* __restrict__ outp) {
  __shared__ __align__(16) short A_lds[128 * 64];
  __shared__ __align__(16) short B_lds[128 * 64];
  const int tid = threadIdx.x, lane = tid & 63, wave = tid >> 6;
  const int row0 = blockIdx.x * 128, col0 = blockIdx.y * 128;
  const int z = (MODE == 0) ? blockIdx.z : 3;
  const short* Bsrc = Wt + (size_t)z * 262144;   // [512 n][512 k]
  const int wr = wave >> 1, wc = wave & 1;

  f32x4 acc[4][4];
  const f32x4 zf = {0.f, 0.f, 0.f, 0.f};
  #pragma unroll
  for (int mi = 0; mi < 4; ++mi)
    #pragma unroll
    for (int ni = 0; ni < 4; ++ni) acc[mi][ni] = zf;

  for (int k0 = 0; k0 < 512; k0 += 64) {
    __syncthreads();
    #pragma unroll
    for (int j = 0; j < 4; ++j) {
      int chunk = j * 256 + wave * 64 + lane;   // 1024 chunks of 8 bf16
      int row = chunk >> 3;
      int cc = (chunk & 7) ^ (row & 7);
      gload_lds16(Abuf + (size_t)(row0 + row) * 512 + k0 + cc * 8,
                  &A_lds[(j * 256 + wave * 64) * 8]);
      gload_lds16(Bsrc + (size_t)(col0 + row) * 512 + k0 + cc * 8,
                  &B_lds[(j * 256 + wave * 64) * 8]);
    }
    __syncthreads();
    #pragma unroll
    for (int kk = 0; kk < 2; ++kk) {
      short8 af[4], bf[4];
      #pragma unroll
      for (int mi = 0; mi < 4; ++mi) {
        int r = wr * 64 + mi * 16 + (lane & 15);
        int cs = (kk * 4 + (lane >> 4)) ^ (r & 7);
        af[mi] = *(const short8*)&A_lds[r * 64 + cs * 8];
      }
      #pragma unroll
      for (int ni = 0; ni < 4; ++ni) {
        int r = wc * 64 + ni * 16 + (lane & 15);
        int cs = (kk * 4 + (lane >> 4)) ^ (r & 7);
        bf[ni] = *(const short8*)&B_lds[r * 64 + cs * 8];
      }
      #pragma unroll
      for (int mi = 0; mi < 4; ++mi)
        #pragma unroll
        for (int ni = 0; ni < 4; ++ni)
          acc[mi][ni] = mfma_bf16(af[mi], bf[ni], acc[mi][ni]);
    }
  }

  if (MODE == 0) {
    const float* bias = (z == 0) ? bias0 : (z == 1) ? bias1 : bias2;
    #pragma unroll
    for (int ni = 0; ni < 4; ++ni) {
      int n = col0 + wc * 64 + ni * 16 + (lane & 15);
      float bsv = bias[n];
      int hhd = n >> 6, dd = n & 63;
      #pragma unroll
      for (int mi = 0; mi < 4; ++mi) {
        int rg = row0 + wr * 64 + mi * 16 + ((lane >> 4) << 2);
        int bb = rg >> 11, ss = rg & 2047;
        size_t bhI = (size_t)(bb * NH_ + hhd);
        if (z == 0) {
          size_t base = bhI << 17;
          #pragma unroll
          for (int j = 0; j < 4; ++j)
            Qb[base + (size_t)(ss + j) * 64 + dd] = (short)f2bf(acc[mi][ni][j] + bsv);
        } else if (z == 1) {
          // K fragment granules: [bh][t][half*4+c][lane2=dh*32+lr][e], e along d
          int c = dd >> 4, dh = (dd >> 3) & 1, e = dd & 7;
          int t = ss >> 6, half = (ss >> 5) & 1, lr = ss & 31;
          size_t g = (bhI * 32 + t) * 4096 + (size_t)(half * 4 + c) * 512 + e;
          #pragma unroll
          for (int j = 0; j < 4; ++j)
            Kb2[g + (size_t)(dh * 32 + lr + j) * 8] = (short)f2bf(acc[mi][ni][j] + bsv);
        } else {
          // V fragment granules: [bh][t][kc*2+dhalf][lane2=kh*32+lr][e], e along kpos
          int dhalf = dd >> 5, lr = dd & 31;
          int t = ss >> 6, ks = ss & 63;
          int kc = ks >> 4, kh = (ks >> 3) & 1, e0 = ks & 7;
          size_t g = (bhI * 32 + t) * 4096 + (size_t)(kc * 2 + dhalf) * 512 +
                     (size_t)(kh * 32 + lr) * 8 + e0;
          short4v pk;
          #pragma unroll
          for (int j = 0; j < 4; ++j) pk[j] = (short)f2bf(acc[mi][ni][j] + bsv);
          *(short4v*)&Vb2[g] = pk;
        }
      }
    }
  } else {
    #pragma unroll
    for (int ni = 0; ni < 4; ++ni) {
      int n = col0 + wc * 64 + ni * 16 + (lane & 15);
      float bsv = bias0[n];
      #pragma unroll
      for (int mi = 0; mi < 4; ++mi) {
        int rg = row0 + wr * 64 + mi * 16 + ((lane >> 4) << 2);
        #pragma unroll
        for (int j = 0; j < 4; ++j)
          outp[(size_t)(rg + j) * 512 + n] = acc[mi][ni][j] + bsv;
      }
    }
  }
}

// ---------------- kernel 4: flash attention ----------------
// grid (S/128, H, B), 512 threads = 8 waves = 4 q-groups x 2 k-segments.
// Wave: 32 q-rows, kpos range seg*1024..+1024, 16 tiles of 64. All LDS reads
// are contiguous base+lane*16 (fragment-linear layout) -> bank-conflict-free.
__global__ __launch_bounds__(512) void sa_attn(const short* __restrict__ Qb,
                                               const short* __restrict__ Kb2,
                                               const short* __restrict__ Vb2,
                                               short* __restrict__ Ob) {
  __shared__ __align__(16) short K_lds[2][2][4096];   // [seg][buf] 8 KB tiles
  __shared__ __align__(16) short V_lds[2][2][4096];
  const int tid = threadIdx.x, lane = tid & 63, wave = tid >> 6;
  const int seg = wave >> 2, wq = wave & 3;
  const int hb = blockIdx.y, b = blockIdx.z;
  const size_t bh32 = ((size_t)(b * NH_ + hb)) * 32;
  const int q0w = blockIdx.x * 128 + wq * 32;
  const int l31 = lane & 31, hh = lane >> 5, base32 = lane & 32;
  const int stid = tid & 255;
  const int lo = lane * 8;                            // lane granule offset (shorts)

  // Q frags (B-operand): q = q0w + l31, d = c*16 + hh*8 + {0..7}
  const size_t bhq = ((size_t)(b * NH_ + hb)) << 17;
  short8 qf[4];
  #pragma unroll
  for (int c = 0; c < 4; ++c)
    qf[c] = *(const short8*)&Qb[bhq + (size_t)(q0w + l31) * 64 + c * 16 + hh * 8];

  f32x16 o0 = {}, o1 = {};
  float mrow = -3.0e38f, lrow = 0.f;
  const float cf = 0.18033688011112042f;   // log2(e)/8

  auto STAGE = [&](int sbuf, int tg) {
    const short* Ks = Kb2 + (bh32 + tg) * 4096;
    const short* Vs = Vb2 + (bh32 + tg) * 4096;
    #pragma unroll
    for (int j = 0; j < 2; ++j) {
      int gr = j * 256 + stid;                       // granule index 0..511
      gload_lds16(Ks + (size_t)gr * 8, &K_lds[seg][sbuf][(j * 256 + wq * 64) * 8]);
      gload_lds16(Vs + (size_t)gr * 8, &V_lds[seg][sbuf][(j * 256 + wq * 64) * 8]);
    }
  };

  STAGE(0, seg * 16);
  __syncthreads();

  for (int t = 0; t < 16; ++t) {
    const int buf = t & 1;
    if (t + 1 < 16) STAGE(buf ^ 1, seg * 16 + t + 1);
    const short* Kt = &K_lds[seg][buf][0];
    const short* Vt = &V_lds[seg][buf][0];

    // ---- QK^T (swapped): lane holds q=l31; kpos = kt*32+(r&3)+8*(r>>2)+4*hh
    f32x16 sc0 = {}, sc1 = {};
    #pragma unroll
    for (int c = 0; c < 4; ++c) {
      short8 kf0 = *(const short8*)&Kt[c * 512 + lo];
      short8 kf1 = *(const short8*)&Kt[(4 + c) * 512 + lo];
      sc0 = mfma32(kf0, qf[c], sc0);
      sc1 = mfma32(kf1, qf[c], sc1);
    }

    // ---- softmax (tree-shaped reductions, one cross-half swap)
    float mv[8];
    #pragma unroll
    for (int i = 0; i < 8; ++i)
      mv[i] = fmaxf(fmaxf(sc0[2 * i], sc0[2 * i + 1]),
                    fmaxf(sc1[2 * i], sc1[2 * i + 1]));
    mv[0] = fmaxf(mv[0], mv[4]); mv[1] = fmaxf(mv[1], mv[5]);
    mv[2] = fmaxf(mv[2], mv[6]); mv[3] = fmaxf(mv[3], mv[7]);
    float mx = fmaxf(fmaxf(mv[0], mv[1]), fmaxf(mv[2], mv[3]));
    mx = fmaxf(mx, __shfl_xor(mx, 32));
    float mnew = fmaxf(mrow, mx);
    bool nores = __all(mnew == mrow);
    float mc = mnew * cf;

    float psum[4] = {0.f, 0.f, 0.f, 0.f};
    #pragma unroll
    for (int r = 0; r < 16; ++r) {
      float p0 = __builtin_amdgcn_exp2f(sc0[r] * cf - mc);
      float p1 = __builtin_amdgcn_exp2f(sc1[r] * cf - mc);
      sc0[r] = p0; sc1[r] = p1;
      psum[r & 3] += p0 + p1;
    }
    float s = (psum[0] + psum[1]) + (psum[2] + psum[3]);
    s += __shfl_xor(s, 32);

    if (nores) {
      lrow += s;
    } else {
      float al = __builtin_amdgcn_exp2f(mrow * cf - mc);
      mrow = mnew;
      lrow = lrow * al + s;
      #pragma unroll
      for (int r = 0; r < 16; ++r) {
        int qr = (r & 3) + 8 * (r >> 2) + 4 * hh;
        float ar = __shfl(al, base32 + qr);
        o0[r] *= ar; o1[r] *= ar;
      }
    }

    // ---- pack P to bf16 words
    unsigned int W[16], Sx[16];
    #pragma unroll
    for (int m = 0; m < 4; ++m) {
      W[2 * m]         = packbf(sc0[4 * m],     sc0[4 * m + 1]);
      W[2 * m + 1]     = packbf(sc0[4 * m + 2], sc0[4 * m + 3]);
      W[8 + 2 * m]     = packbf(sc1[4 * m],     sc1[4 * m + 1]);
      W[8 + 2 * m + 1] = packbf(sc1[4 * m + 2], sc1[4 * m + 3]);
    }
    #pragma unroll
    for (int i = 0; i < 16; ++i)
      Sx[i] = (unsigned int)__shfl_xor((int)W[i], 32);

    // ---- PV: o += P(32q x 64k) @ V(64k x 64d)
    #pragma unroll
    for (int kc = 0; kc < 4; ++kc) {
      unsigned int f0 = hh ? Sx[4 * kc + 2] : W[4 * kc];
      unsigned int f1 = hh ? Sx[4 * kc + 3] : W[4 * kc + 1];
      unsigned int f2 = hh ? W[4 * kc + 2]  : Sx[4 * kc];
      unsigned int f3 = hh ? W[4 * kc + 3]  : Sx[4 * kc + 1];
      u32x4 paw = {f0, f1, f2, f3};
      short8 pa = __builtin_bit_cast(short8, paw);
      short8 vf0 = *(const short8*)&Vt[(kc * 2) * 512 + lo];
      short8 vf1 = *(const short8*)&Vt[(kc * 2 + 1) * 512 + lo];
      o0 = mfma32(pa, vf0, o0);
      o1 = mfma32(pa, vf1, o1);
    }
    __syncthreads();   // drains prefetch + protects buf reuse
  }

  // ---- combine the two k-segments via LDS, then write Ob
  float* Ml = (float*)&V_lds[0][0][0];   // 4 groups x 64 floats
  float* Ox = (float*)&K_lds[0][0][0];   // 4 groups x 2048 floats
  if (seg == 1) {
    if (lane < 32) { Ml[wq * 64 + lane] = mrow; Ml[wq * 64 + 32 + lane] = lrow; }
    float* Og = Ox + wq * 2048;
    #pragma unroll
    for (int r = 0; r < 16; ++r) {
      int qr = (r & 3) + 8 * (r >> 2) + 4 * hh;
      Og[qr * 64 + l31]      = o0[r];
      Og[qr * 64 + 32 + l31] = o1[r];
    }
  }
  __syncthreads();
  if (seg == 0) {
    float m1 = Ml[wq * 64 + l31], l1 = Ml[wq * 64 + 32 + l31];
    float M = fmaxf(mrow, m1);
    float a0 = __builtin_amdgcn_exp2f((mrow - M) * cf);
    float a1 = __builtin_amdgcn_exp2f((m1 - M) * cf);
    float inv = 1.f / (lrow * a0 + l1 * a1);
    float* Og = Ox + wq * 2048;
    #pragma unroll
    for (int r = 0; r < 16; ++r) {
      int qr = (r & 3) + 8 * (r >> 2) + 4 * hh;
      float A0 = __shfl(a0, base32 + qr);
      float A1 = __shfl(a1, base32 + qr);
      float I  = __shfl(inv, base32 + qr);
      float v0 = (o0[r] * A0 + Og[qr * 64 + l31] * A1) * I;
      float v1 = (o1[r] * A0 + Og[qr * 64 + 32 + l31] * A1) * I;
      size_t rowb = ((size_t)(b * S_ + q0w + qr)) * 512 + hb * 64;
      Ob[rowb + l31]      = (short)f2bf(v0);
      Ob[rowb + 32 + l31] = (short)f2bf(v1);
    }
  }
}

// ---------------- launcher ----------------
extern "C" void kernel_launch(void* const* d_in, const int* in_sizes, int n_in,
                              void* d_out, int out_size, void* d_ws, size_t ws_size,
                              hipStream_t stream) {
  const float* x  = (const float*)d_in[0];
  const float* Wq = (const float*)d_in[1];
  const float* bq = (const float*)d_in[2];
  const float* Wk = (const float*)d_in[3];
  const float* bk = (const float*)d_in[4];
  const float* Wv = (const float*)d_in[5];
  const float* bv = (const float*)d_in[6];
  const float* Wo = (const float*)d_in[7];
  const float* bo = (const float*)d_in[8];
  float* out = (float*)d_out;

  short* ws = (short*)d_ws;
  short* xb  = ws;                  // 8192*512  = 4,194,304 shorts
  short* Wt  = ws + 4194304;        // 4*512*512 = 1,048,576
  short* Qb  = ws + 5242880;        // (B,H,S,D) = 4,194,304
  short* Kb2 = ws + 9437184;        // K fragment-order = 4,194,304
  short* Vb2 = ws + 13631488;       // V fragment-order = 4,194,304
  short* Ob  = ws + 17825792;       // (B*S, 512) = 4,194,304  (end: 44 MB)

  hipLaunchKernelGGL(sa_convert_x, dim3(2048), dim3(256), 0, stream, x, xb);
  hipLaunchKernelGGL(sa_transpose_w, dim3(16, 16, 4), dim3(32, 8), 0, stream,
                     Wq, Wk, Wv, Wo, Wt);
  hipLaunchKernelGGL(sa_gemm<0>, dim3(64, 4, 3), dim3(256), 0, stream,
                     xb, Wt, bq, bk, bv, Qb, Kb2, Vb2, (float*)nullptr);
  hipLaunchKernelGGL(sa_attn, dim3(16, 8, 4), dim3(512), 0, stream, Qb, Kb2, Vb2, Ob);
  hipLaunchKernelGGL(sa_gemm<1>, dim3(64, 4, 1), dim3(256), 0, stream,
                     Ob, Wt, bo, (const float*)nullptr, (const float*)nullptr,
                     (short*)nullptr, (short*)nullptr, (short*)nullptr, out);
}

// Round 5
// 107.182 us; speedup vs baseline: 1.5730x; 1.1434x over previous
//
#include <hip/hip_runtime.h>
#include <stdint.h>

#define B_   4
#define S_   2048
#define IN_  512
#define HID_ 512
#define NH_  8
#define HD_  64
#define M_   (B_*S_)   // 8192

typedef __attribute__((ext_vector_type(8)))  short  short8;
typedef __attribute__((ext_vector_type(4)))  short  short4v;
typedef __attribute__((ext_vector_type(4)))  float  f32x4;
typedef __attribute__((ext_vector_type(16))) float  f32x16;
typedef __attribute__((ext_vector_type(8)))  __bf16 bf16x8;
typedef __attribute__((ext_vector_type(2)))  __bf16 bf16x2;
typedef __attribute__((ext_vector_type(4)))  unsigned int u32x4;
typedef __attribute__((ext_vector_type(2)))  unsigned int u32x2;

// fp32 -> bf16 bits, round-to-nearest-even
__device__ __forceinline__ unsigned short f2bf(float f) {
  union { float f; unsigned u; } v; v.f = f;
  unsigned r = (v.u + 0x7fffu + ((v.u >> 16) & 1u)) >> 16;
  return (unsigned short)r;
}

// pack 2 f32 -> u32 of 2 bf16 (v_cvt_pk_bf16_f32)
__device__ __forceinline__ unsigned int packbf(float a, float b) {
  bf16x2 t; t[0] = (__bf16)a; t[1] = (__bf16)b;
  return __builtin_bit_cast(unsigned int, t);
}

// lane-half swap: r[0] = [a.lo | b.lo], r[1] = [a.hi | b.hi]
__device__ __forceinline__ u32x2 pl32swap(unsigned int a, unsigned int b) {
  return __builtin_amdgcn_permlane32_swap(a, b, false, false);
}

__device__ __forceinline__ f32x4 mfma_bf16(short8 a, short8 b, f32x4 c) {
  return __builtin_amdgcn_mfma_f32_16x16x32_bf16(
      __builtin_bit_cast(bf16x8, a), __builtin_bit_cast(bf16x8, b), c, 0, 0, 0);
}

__device__ __forceinline__ f32x16 mfma32(short8 a, short8 b, f32x16 c) {
  return __builtin_amdgcn_mfma_f32_32x32x16_bf16(
      __builtin_bit_cast(bf16x8, a), __builtin_bit_cast(bf16x8, b), c, 0, 0, 0);
}

// async global->LDS, 16B per lane; dst wave-uniform base (+lane*16 implicit)
__device__ __forceinline__ void gload_lds16(const void* g, void* l) {
  __builtin_amdgcn_global_load_lds(
      (__attribute__((address_space(1))) void*)g,
      (__attribute__((address_space(3))) void*)l, 16, 0, 0);
}

// ---------------- kernel 1: x (fp32) -> xb (bf16) ----------------
__global__ __launch_bounds__(256) void sa_convert_x(const float* __restrict__ x,
                                                    short* __restrict__ xb) {
  int i = (blockIdx.x * 256 + threadIdx.x) * 8;
  const float4* p = (const float4*)&x[i];
  float4 a = p[0], b2 = p[1];
  short8 r;
  r[0] = (short)f2bf(a.x);  r[1] = (short)f2bf(a.y);
  r[2] = (short)f2bf(a.z);  r[3] = (short)f2bf(a.w);
  r[4] = (short)f2bf(b2.x); r[5] = (short)f2bf(b2.y);
  r[6] = (short)f2bf(b2.z); r[7] = (short)f2bf(b2.w);
  *(short8*)&xb[i] = r;
}

// ---------------- kernel 2: W (512x512 fp32) -> Wt (bf16, transposed) ----------------
__global__ __launch_bounds__(256) void sa_transpose_w(const float* __restrict__ Wq,
                                                      const float* __restrict__ Wk,
                                                      const float* __restrict__ Wv,
                                                      const float* __restrict__ Wo,
                                                      short* __restrict__ Wt) {
  __shared__ float tile[32][33];
  const int z = blockIdx.z;
  const float* src = (z == 0) ? Wq : (z == 1) ? Wk : (z == 2) ? Wv : Wo;
  const int k0 = blockIdx.y * 32, n0 = blockIdx.x * 32;
  const int tx = threadIdx.x, ty = threadIdx.y;   // (32, 8)
  #pragma unroll
  for (int i = 0; i < 32; i += 8)
    tile[ty + i][tx] = src[(size_t)(k0 + ty + i) * 512 + n0 + tx];
  __syncthreads();
  short* dst = Wt + (size_t)z * 262144;
  #pragma unroll
  for (int i = 0; i < 32; i += 8)
    dst[(size_t)(n0 + ty + i) * 512 + k0 + tx] = (short)f2bf(tile[tx][ty + i]);
}

// ---------------- GEMM: C(8192x512) = A(8192x512,bf16) @ W(512x512) + bias ----------------
// 1-D grid with XCD swizzle so the 4 col-blocks sharing an A-panel land on one XCD.
// MODE 0: 768 blocks, z in {0,1,2} -> Q row-major, K/V fragment-order
// MODE 1: 256 blocks, z=3 (Wo) -> fp32 d_out with bo
template <int MODE>
__global__ __launch_bounds__(256) void sa_gemm(const short* __restrict__ Abuf,
                                               const short* __restrict__ Wt,
                                               const float* __restrict__ bias0,
                                               const float* __restrict__ bias1,
                                               const float* __restrict__ bias2,
                                               short* __restrict__ Qb,
                                               short* __restrict__ Kb2,
                                               short* __restrict__ Vb2,
                                               float* __restrict__ outp) {
  __shared__ __align__(16) short A_lds[128 * 64];
  __shared__ __align__(16) short B_lds[128 * 64];
  const int tid = threadIdx.x, lane = tid & 63, wave = tid >> 6;
  const int dd0 = blockIdx.x;
  const int L = (MODE == 0) ? ((dd0 & 7) * 96 + (dd0 >> 3))
                            : ((dd0 & 7) * 32 + (dd0 >> 3));
  const int by = L & 3, bx = (L >> 2) & 63;
  const int z = (MODE == 0) ? (L >> 8) : 3;
  const int row0 = bx * 128, col0 = by * 128;
  const short* Bsrc = Wt + (size_t)z * 262144;   // [512 n][512 k]
  const int wr = wave >> 1, wc = wave & 1;

  f32x4 acc[4][4];
  const f32x4 zf = {0.f, 0.f, 0.f, 0.f};
  #pragma unroll
  for (int mi = 0; mi < 4; ++mi)
    #pragma unroll
    for (int ni = 0; ni < 4; ++ni) acc[mi][ni] = zf;

  for (int k0 = 0; k0 < 512; k0 += 64) {
    __syncthreads();
    #pragma unroll
    for (int j = 0; j < 4; ++j) {
      int chunk = j * 256 + wave * 64 + lane;   // 1024 chunks of 8 bf16
      int row = chunk >> 3;
      int cc = (chunk & 7) ^ (row & 7);
      gload_lds16(Abuf + (size_t)(row0 + row) * 512 + k0 + cc * 8,
                  &A_lds[(j * 256 + wave * 64) * 8]);
      gload_lds16(Bsrc + (size_t)(col0 + row) * 512 + k0 + cc * 8,
                  &B_lds[(j * 256 + wave * 64) * 8]);
    }
    __syncthreads();
    #pragma unroll
    for (int kk = 0; kk < 2; ++kk) {
      short8 af[4], bf[4];
      #pragma unroll
      for (int mi = 0; mi < 4; ++mi) {
        int r = wr * 64 + mi * 16 + (lane & 15);
        int cs = (kk * 4 + (lane >> 4)) ^ (r & 7);
        af[mi] = *(const short8*)&A_lds[r * 64 + cs * 8];
      }
      #pragma unroll
      for (int ni = 0; ni < 4; ++ni) {
        int r = wc * 64 + ni * 16 + (lane & 15);
        int cs = (kk * 4 + (lane >> 4)) ^ (r & 7);
        bf[ni] = *(const short8*)&B_lds[r * 64 + cs * 8];
      }
      #pragma unroll
      for (int mi = 0; mi < 4; ++mi)
        #pragma unroll
        for (int ni = 0; ni < 4; ++ni)
          acc[mi][ni] = mfma_bf16(af[mi], bf[ni], acc[mi][ni]);
    }
  }

  if (MODE == 0) {
    const float* bias = (z == 0) ? bias0 : (z == 1) ? bias1 : bias2;
    #pragma unroll
    for (int ni = 0; ni < 4; ++ni) {
      int n = col0 + wc * 64 + ni * 16 + (lane & 15);
      float bsv = bias[n];
      int hhd = n >> 6, dd = n & 63;
      #pragma unroll
      for (int mi = 0; mi < 4; ++mi) {
        int rg = row0 + wr * 64 + mi * 16 + ((lane >> 4) << 2);
        int bb = rg >> 11, ss = rg & 2047;
        size_t bhI = (size_t)(bb * NH_ + hhd);
        if (z == 0) {
          size_t base = bhI << 17;
          #pragma unroll
          for (int j = 0; j < 4; ++j)
            Qb[base + (size_t)(ss + j) * 64 + dd] = (short)f2bf(acc[mi][ni][j] + bsv);
        } else if (z == 1) {
          // K fragment granules: [bh][t][half*4+c][lane2=dh*32+lr][e], e along d
          int c = dd >> 4, dh = (dd >> 3) & 1, e = dd & 7;
          int t = ss >> 6, half = (ss >> 5) & 1, lr = ss & 31;
          size_t g = (bhI * 32 + t) * 4096 + (size_t)(half * 4 + c) * 512 + e;
          #pragma unroll
          for (int j = 0; j < 4; ++j)
            Kb2[g + (size_t)(dh * 32 + lr + j) * 8] = (short)f2bf(acc[mi][ni][j] + bsv);
        } else {
          // V fragment granules: [bh][t][kc*2+dhalf][lane2=kh*32+lr][e], e along kpos
          int dhalf = dd >> 5, lr = dd & 31;
          int t = ss >> 6, ks = ss & 63;
          int kc = ks >> 4, kh = (ks >> 3) & 1, e0 = ks & 7;
          size_t g = (bhI * 32 + t) * 4096 + (size_t)(kc * 2 + dhalf) * 512 +
                     (size_t)(kh * 32 + lr) * 8 + e0;
          short4v pk;
          #pragma unroll
          for (int j = 0; j < 4; ++j) pk[j] = (short)f2bf(acc[mi][ni][j] + bsv);
          *(short4v*)&Vb2[g] = pk;
        }
      }
    }
  } else {
    #pragma unroll
    for (int ni = 0; ni < 4; ++ni) {
      int n = col0 + wc * 64 + ni * 16 + (lane & 15);
      float bsv = bias0[n];
      #pragma unroll
      for (int mi = 0; mi < 4; ++mi) {
        int rg = row0 + wr * 64 + mi * 16 + ((lane >> 4) << 2);
        #pragma unroll
        for (int j = 0; j < 4; ++j)
          outp[(size_t)(rg + j) * 512 + n] = acc[mi][ni][j] + bsv;
      }
    }
  }
}

// ---------------- kernel 4: flash attention ----------------
// 1-D grid 512 (XCD-swizzled), 512 threads = 4 q-groups x 2 k-segments.
// T15: QK(t+1) overlaps softmax(t). K staged 2-ahead, V 1-ahead, 1 barrier/iter.
// T13: defer-max THR=8 (raw-score units) -> steady-state rescale never fires.
__global__ __launch_bounds__(512) void sa_attn(const short* __restrict__ Qb,
                                               const short* __restrict__ Kb2,
                                               const short* __restrict__ Vb2,
                                               short* __restrict__ Ob) {
  __shared__ __align__(16) short K_lds[2][2][4096];   // [seg][buf] 8 KB tiles
  __shared__ __align__(16) short V_lds[2][2][4096];
  const int tid = threadIdx.x, lane = tid & 63, wave = tid >> 6;
  const int seg = wave >> 2, wq = wave & 3;
  const int dd0 = blockIdx.x;                 // 512 = 8 * 64, bijective
  const int wg = (dd0 & 7) * 64 + (dd0 >> 3); // groups all q-tiles of 4 (b,h) per XCD
  const int qb = wg & 15, hb = (wg >> 4) & 7, b = wg >> 7;
  const size_t bh32 = ((size_t)(b * NH_ + hb)) * 32;
  const int q0w = qb * 128 + wq * 32;
  const int l31 = lane & 31, hh = lane >> 5, base32 = lane & 32;
  const int stid = tid & 255;
  const int lo = lane * 8;
  const int sg16 = seg * 16;

  // Q frags (B-operand): q = q0w + l31, d = c*16 + hh*8 + {0..7}
  const size_t bhq = ((size_t)(b * NH_ + hb)) << 17;
  short8 qf[4];
  #pragma unroll
  for (int c = 0; c < 4; ++c)
    qf[c] = *(const short8*)&Qb[bhq + (size_t)(q0w + l31) * 64 + c * 16 + hh * 8];

  f32x16 o0 = {}, o1 = {};
  float mrow = -3.0e38f, lrow = 0.f;
  const float cf = 0.18033688011112042f;   // log2(e)/8

  auto STAGE_K = [&](int sbuf, int tg) {
    const short* Ks = Kb2 + (bh32 + tg) * 4096;
    gload_lds16(Ks + (size_t)stid * 8,         &K_lds[seg][sbuf][wq * 512]);
    gload_lds16(Ks + (size_t)(256 + stid) * 8, &K_lds[seg][sbuf][2048 + wq * 512]);
  };
  auto STAGE_V = [&](int sbuf, int tg) {
    const short* Vs = Vb2 + (bh32 + tg) * 4096;
    gload_lds16(Vs + (size_t)stid * 8,         &V_lds[seg][sbuf][wq * 512]);
    gload_lds16(Vs + (size_t)(256 + stid) * 8, &V_lds[seg][sbuf][2048 + wq * 512]);
  };
  auto QK = [&](int nbuf, f32x16& s0, f32x16& s1) {
    const short* Kt = &K_lds[seg][nbuf][0];
    s0 = 0.f; s1 = 0.f;
    __builtin_amdgcn_s_setprio(1);
    #pragma unroll
    for (int c = 0; c < 4; ++c) {
      short8 kf0 = *(const short8*)&Kt[c * 512 + lo];
      short8 kf1 = *(const short8*)&Kt[(4 + c) * 512 + lo];
      s0 = mfma32(kf0, qf[c], s0);
      s1 = mfma32(kf1, qf[c], s1);
    }
    __builtin_amdgcn_s_setprio(0);
  };

  auto BODY = [&](f32x16& scc0, f32x16& scc1, f32x16& scn0, f32x16& scn1, int t) {
    const int buf = t & 1, nbuf = buf ^ 1;
    // staged stores: K two-ahead into buf, V one-ahead into nbuf (disjoint from
    // this iter's reads: QK reads K[nbuf], PV reads V[buf])
    if (t + 2 < 16) STAGE_K(buf, sg16 + t + 2);
    if (t + 1 < 16) {
      STAGE_V(nbuf, sg16 + t + 1);
      QK(nbuf, scn0, scn1);          // MFMA pipe crunches during softmax below
    }

    // ---- softmax(scc): tree max, THR-deferred rescale ----
    float t8[8];
    #pragma unroll
    for (int i = 0; i < 8; ++i)
      t8[i] = fmaxf(fmaxf(scc0[2 * i], scc0[2 * i + 1]),
                    fmaxf(scc1[2 * i], scc1[2 * i + 1]));
    t8[0] = fmaxf(t8[0], t8[4]); t8[1] = fmaxf(t8[1], t8[5]);
    t8[2] = fmaxf(t8[2], t8[6]); t8[3] = fmaxf(t8[3], t8[7]);
    float mx = fmaxf(fmaxf(t8[0], t8[1]), fmaxf(t8[2], t8[3]));
    mx = fmaxf(mx, __shfl_xor(mx, 32));
    if (!__all(mx <= mrow + 8.f)) {        // fires ~once (first tile)
      float mnew = fmaxf(mrow, mx);
      float al = __builtin_amdgcn_exp2f((mrow - mnew) * cf);
      lrow *= al;
      #pragma unroll
      for (int r = 0; r < 16; ++r) {
        int qr = (r & 3) + 8 * (r >> 2) + 4 * hh;
        float ar = __shfl(al, base32 + qr);
        o0[r] *= ar; o1[r] *= ar;
      }
      mrow = mnew;
    }
    float mc = mrow * cf;
    float ps0 = 0.f, ps1 = 0.f, ps2 = 0.f, ps3 = 0.f;
    #pragma unroll
    for (int r = 0; r < 16; ++r) {
      float p0 = __builtin_amdgcn_exp2f(scc0[r] * cf - mc);
      float p1 = __builtin_amdgcn_exp2f(scc1[r] * cf - mc);
      scc0[r] = p0; scc1[r] = p1;
      if ((r & 3) == 0) { ps0 += p0 + p1; }
      else if ((r & 3) == 1) { ps1 += p0 + p1; }
      else if ((r & 3) == 2) { ps2 += p0 + p1; }
      else { ps3 += p0 + p1; }
    }
    float s = (ps0 + ps1) + (ps2 + ps3);
    s += __shfl_xor(s, 32);
    lrow += s;

    // ---- pack P to bf16 words ----
    unsigned int W[16];
    #pragma unroll
    for (int m = 0; m < 4; ++m) {
      W[2 * m]         = packbf(scc0[4 * m],     scc0[4 * m + 1]);
      W[2 * m + 1]     = packbf(scc0[4 * m + 2], scc0[4 * m + 3]);
      W[8 + 2 * m]     = packbf(scc1[4 * m],     scc1[4 * m + 1]);
      W[8 + 2 * m + 1] = packbf(scc1[4 * m + 2], scc1[4 * m + 3]);
    }

    // ---- PV: o += P(32q x 64k) @ V(64k x 64d); frag halves via permlane32_swap
    const short* Vt = &V_lds[seg][buf][0];
    __builtin_amdgcn_s_setprio(1);
    #pragma unroll
    for (int kc = 0; kc < 4; ++kc) {
      u32x2 p02 = pl32swap(W[4 * kc],     W[4 * kc + 2]);
      u32x2 p13 = pl32swap(W[4 * kc + 1], W[4 * kc + 3]);
      u32x4 paw = {p02[0], p13[0], p02[1], p13[1]};
      short8 pa = __builtin_bit_cast(short8, paw);
      short8 vf0 = *(const short8*)&Vt[(kc * 2) * 512 + lo];
      short8 vf1 = *(const short8*)&Vt[(kc * 2 + 1) * 512 + lo];
      o0 = mfma32(pa, vf0, o0);
      o1 = mfma32(pa, vf1, o1);
    }
    __builtin_amdgcn_s_setprio(0);
    __syncthreads();   // drains stage loads; syncs buffer rotation
  };

  // prologue: K(0),K(1),V(0) staged; QK(0) computed
  STAGE_K(0, sg16);
  STAGE_K(1, sg16 + 1);
  STAGE_V(0, sg16);
  __syncthreads();
  f32x16 A0, A1, B0, B1;
  QK(0, A0, A1);
  __syncthreads();   // all waves done reading K[0] before BODY(0) overwrites it

  for (int tt = 0; tt < 8; ++tt) {
    BODY(A0, A1, B0, B1, 2 * tt);
    BODY(B0, B1, A0, A1, 2 * tt + 1);
  }

  // ---- combine the two k-segments via LDS, then write Ob
  float* Ml = (float*)&V_lds[0][0][0];   // 4 groups x 64 floats
  float* Ox = (float*)&K_lds[0][0][0];   // 4 groups x 2048 floats
  if (seg == 1) {
    if (lane < 32) { Ml[wq * 64 + lane] = mrow; Ml[wq * 64 + 32 + lane] = lrow; }
    float* Og = Ox + wq * 2048;
    #pragma unroll
    for (int r = 0; r < 16; ++r) {
      int qr = (r & 3) + 8 * (r >> 2) + 4 * hh;
      Og[qr * 64 + l31]      = o0[r];
      Og[qr * 64 + 32 + l31] = o1[r];
    }
  }
  __syncthreads();
  if (seg == 0) {
    float m1 = Ml[wq * 64 + l31], l1 = Ml[wq * 64 + 32 + l31];
    float M = fmaxf(mrow, m1);
    float a0 = __builtin_amdgcn_exp2f((mrow - M) * cf);
    float a1 = __builtin_amdgcn_exp2f((m1 - M) * cf);
    float inv = 1.f / (lrow * a0 + l1 * a1);
    float* Og = Ox + wq * 2048;
    #pragma unroll
    for (int r = 0; r < 16; ++r) {
      int qr = (r & 3) + 8 * (r >> 2) + 4 * hh;
      float A0b = __shfl(a0, base32 + qr);
      float A1b = __shfl(a1, base32 + qr);
      float I   = __shfl(inv, base32 + qr);
      float v0 = (o0[r] * A0b + Og[qr * 64 + l31] * A1b) * I;
      float v1 = (o1[r] * A0b + Og[qr * 64 + 32 + l31] * A1b) * I;
      size_t rowb = ((size_t)(b * S_ + q0w + qr)) * 512 + hb * 64;
      Ob[rowb + l31]      = (short)f2bf(v0);
      Ob[rowb + 32 + l31] = (short)f2bf(v1);
    }
  }
}

// ---------------- launcher ----------------
extern "C" void kernel_launch(void* const* d_in, const int* in_sizes, int n_in,
                              void* d_out, int out_size, void* d_ws, size_t ws_size,
                              hipStream_t stream) {
  const float* x  = (const float*)d_in[0];
  const float* Wq = (const float*)d_in[1];
  const float* bq = (const float*)d_in[2];
  const float* Wk = (const float*)d_in[3];
  const float* bk = (const float*)d_in[4];
  const float* Wv = (const float*)d_in[5];
  const float* bv = (const float*)d_in[6];
  const float* Wo = (const float*)d_in[7];
  const float* bo = (const float*)d_in[8];
  float* out = (float*)d_out;

  short* ws = (short*)d_ws;
  short* xb  = ws;                  // 8192*512  = 4,194,304 shorts
  short* Wt  = ws + 4194304;        // 4*512*512 = 1,048,576
  short* Qb  = ws + 5242880;        // (B,H,S,D) = 4,194,304
  short* Kb2 = ws + 9437184;        // K fragment-order = 4,194,304
  short* Vb2 = ws + 13631488;       // V fragment-order = 4,194,304
  short* Ob  = ws + 17825792;       // (B*S, 512) = 4,194,304  (end: 44 MB)

  hipLaunchKernelGGL(sa_convert_x, dim3(2048), dim3(256), 0, stream, x, xb);
  hipLaunchKernelGGL(sa_transpose_w, dim3(16, 16, 4), dim3(32, 8), 0, stream,
                     Wq, Wk, Wv, Wo, Wt);
  hipLaunchKernelGGL(sa_gemm<0>, dim3(768), dim3(256), 0, stream,
                     xb, Wt, bq, bk, bv, Qb, Kb2, Vb2, (float*)nullptr);
  hipLaunchKernelGGL(sa_attn, dim3(512), dim3(512), 0, stream, Qb, Kb2, Vb2, Ob);
  hipLaunchKernelGGL(sa_gemm<1>, dim3(256), dim3(256), 0, stream,
                     Ob, Wt, bo, (const float*)nullptr, (const float*)nullptr,
                     (short*)nullptr, (short*)nullptr, (short*)nullptr, out);
}

// Round 6
// 99.608 us; speedup vs baseline: 1.6926x; 1.0760x over previous
//
#include <hip/hip_runtime.h>
#include <stdint.h>

#define B_   4
#define S_   2048
#define IN_  512
#define HID_ 512
#define NH_  8
#define HD_  64
#define M_   (B_*S_)   // 8192

typedef __attribute__((ext_vector_type(8)))  short  short8;
typedef __attribute__((ext_vector_type(4)))  short  short4v;
typedef __attribute__((ext_vector_type(4)))  float  f32x4;
typedef __attribute__((ext_vector_type(16))) float  f32x16;
typedef __attribute__((ext_vector_type(8)))  __bf16 bf16x8;
typedef __attribute__((ext_vector_type(2)))  __bf16 bf16x2;
typedef __attribute__((ext_vector_type(4)))  unsigned int u32x4;
typedef __attribute__((ext_vector_type(2)))  unsigned int u32x2;

// fp32 -> bf16 bits, round-to-nearest-even
__device__ __forceinline__ unsigned short f2bf(float f) {
  union { float f; unsigned u; } v; v.f = f;
  unsigned r = (v.u + 0x7fffu + ((v.u >> 16) & 1u)) >> 16;
  return (unsigned short)r;
}

// pack 2 f32 -> u32 of 2 bf16 (v_cvt_pk_bf16_f32)
__device__ __forceinline__ unsigned int packbf(float a, float b) {
  bf16x2 t; t[0] = (__bf16)a; t[1] = (__bf16)b;
  return __builtin_bit_cast(unsigned int, t);
}

// lane-half swap. r[0] = lanes<32: a(own) | lanes>=32: b(partner)
//                 r[1] = lanes<32: a(partner) | lanes>=32: b(own)
__device__ __forceinline__ u32x2 pl32swap(unsigned int a, unsigned int b) {
  return __builtin_amdgcn_permlane32_swap(a, b, false, false);
}

__device__ __forceinline__ f32x4 mfma_bf16(short8 a, short8 b, f32x4 c) {
  return __builtin_amdgcn_mfma_f32_16x16x32_bf16(
      __builtin_bit_cast(bf16x8, a), __builtin_bit_cast(bf16x8, b), c, 0, 0, 0);
}

__device__ __forceinline__ f32x16 mfma32(short8 a, short8 b, f32x16 c) {
  return __builtin_amdgcn_mfma_f32_32x32x16_bf16(
      __builtin_bit_cast(bf16x8, a), __builtin_bit_cast(bf16x8, b), c, 0, 0, 0);
}

// async global->LDS, 16B per lane; dst wave-uniform base (+lane*16 implicit)
__device__ __forceinline__ void gload_lds16(const void* g, void* l) {
  __builtin_amdgcn_global_load_lds(
      (__attribute__((address_space(1))) void*)g,
      (__attribute__((address_space(3))) void*)l, 16, 0, 0);
}

// ---------------- kernel 1: x (fp32) -> xb (bf16) ----------------
__global__ __launch_bounds__(256) void sa_convert_x(const float* __restrict__ x,
                                                    short* __restrict__ xb) {
  int i = (blockIdx.x * 256 + threadIdx.x) * 8;
  const float4* p = (const float4*)&x[i];
  float4 a = p[0], b2 = p[1];
  short8 r;
  r[0] = (short)f2bf(a.x);  r[1] = (short)f2bf(a.y);
  r[2] = (short)f2bf(a.z);  r[3] = (short)f2bf(a.w);
  r[4] = (short)f2bf(b2.x); r[5] = (short)f2bf(b2.y);
  r[6] = (short)f2bf(b2.z); r[7] = (short)f2bf(b2.w);
  *(short8*)&xb[i] = r;
}

// ---------------- kernel 2: W (512x512 fp32) -> Wt (bf16, transposed) ----------------
__global__ __launch_bounds__(256) void sa_transpose_w(const float* __restrict__ Wq,
                                                      const float* __restrict__ Wk,
                                                      const float* __restrict__ Wv,
                                                      const float* __restrict__ Wo,
                                                      short* __restrict__ Wt) {
  __shared__ float tile[32][33];
  const int z = blockIdx.z;
  const float* src = (z == 0) ? Wq : (z == 1) ? Wk : (z == 2) ? Wv : Wo;
  const int k0 = blockIdx.y * 32, n0 = blockIdx.x * 32;
  const int tx = threadIdx.x, ty = threadIdx.y;   // (32, 8)
  #pragma unroll
  for (int i = 0; i < 32; i += 8)
    tile[ty + i][tx] = src[(size_t)(k0 + ty + i) * 512 + n0 + tx];
  __syncthreads();
  short* dst = Wt + (size_t)z * 262144;
  #pragma unroll
  for (int i = 0; i < 32; i += 8)
    dst[(size_t)(n0 + ty + i) * 512 + k0 + tx] = (short)f2bf(tile[tx][ty + i]);
}

// ---------------- GEMM: C(8192x512) = A(8192x512,bf16) @ W(512x512) + bias ----------------
// 1-D grid with XCD swizzle so the 4 col-blocks sharing an A-panel land on one XCD.
// MODE 0: 768 blocks, z in {0,1,2} -> Q row-major, K/V fragment-order
// MODE 1: 256 blocks, z=3 (Wo) -> fp32 d_out with bo
template <int MODE>
__global__ __launch_bounds__(256) void sa_gemm(const short* __restrict__ Abuf,
                                               const short* __restrict__ Wt,
                                               const float* __restrict__ bias0,
                                               const float* __restrict__ bias1,
                                               const float* __restrict__ bias2,
                                               short* __restrict__ Qb,
                                               short* __restrict__ Kb2,
                                               short* __restrict__ Vb2,
                                               float* __restrict__ outp) {
  __shared__ __align__(16) short A_lds[128 * 64];
  __shared__ __align__(16) short B_lds[128 * 64];
  const int tid = threadIdx.x, lane = tid & 63, wave = tid >> 6;
  const int dd0 = blockIdx.x;
  const int L = (MODE == 0) ? ((dd0 & 7) * 96 + (dd0 >> 3))
                            : ((dd0 & 7) * 32 + (dd0 >> 3));
  const int by = L & 3, bx = (L >> 2) & 63;
  const int z = (MODE == 0) ? (L >> 8) : 3;
  const int row0 = bx * 128, col0 = by * 128;
  const short* Bsrc = Wt + (size_t)z * 262144;   // [512 n][512 k]
  const int wr = wave >> 1, wc = wave & 1;

  f32x4 acc[4][4];
  const f32x4 zf = {0.f, 0.f, 0.f, 0.f};
  #pragma unroll
  for (int mi = 0; mi < 4; ++mi)
    #pragma unroll
    for (int ni = 0; ni < 4; ++ni) acc[mi][ni] = zf;

  for (int k0 = 0; k0 < 512; k0 += 64) {
    __syncthreads();
    #pragma unroll
    for (int j = 0; j < 4; ++j) {
      int chunk = j * 256 + wave * 64 + lane;   // 1024 chunks of 8 bf16
      int row = chunk >> 3;
      int cc = (chunk & 7) ^ (row & 7);
      gload_lds16(Abuf + (size_t)(row0 + row) * 512 + k0 + cc * 8,
                  &A_lds[(j * 256 + wave * 64) * 8]);
      gload_lds16(Bsrc + (size_t)(col0 + row) * 512 + k0 + cc * 8,
                  &B_lds[(j * 256 + wave * 64) * 8]);
    }
    __syncthreads();
    #pragma unroll
    for (int kk = 0; kk < 2; ++kk) {
      short8 af[4], bf[4];
      #pragma unroll
      for (int mi = 0; mi < 4; ++mi) {
        int r = wr * 64 + mi * 16 + (lane & 15);
        int cs = (kk * 4 + (lane >> 4)) ^ (r & 7);
        af[mi] = *(const short8*)&A_lds[r * 64 + cs * 8];
      }
      #pragma unroll
      for (int ni = 0; ni < 4; ++ni) {
        int r = wc * 64 + ni * 16 + (lane & 15);
        int cs = (kk * 4 + (lane >> 4)) ^ (r & 7);
        bf[ni] = *(const short8*)&B_lds[r * 64 + cs * 8];
      }
      #pragma unroll
      for (int mi = 0; mi < 4; ++mi)
        #pragma unroll
        for (int ni = 0; ni < 4; ++ni)
          acc[mi][ni] = mfma_bf16(af[mi], bf[ni], acc[mi][ni]);
    }
  }

  if (MODE == 0) {
    const float* bias = (z == 0) ? bias0 : (z == 1) ? bias1 : bias2;
    #pragma unroll
    for (int ni = 0; ni < 4; ++ni) {
      int n = col0 + wc * 64 + ni * 16 + (lane & 15);
      float bsv = bias[n];
      int hhd = n >> 6, dd = n & 63;
      #pragma unroll
      for (int mi = 0; mi < 4; ++mi) {
        int rg = row0 + wr * 64 + mi * 16 + ((lane >> 4) << 2);
        int bb = rg >> 11, ss = rg & 2047;
        size_t bhI = (size_t)(bb * NH_ + hhd);
        if (z == 0) {
          size_t base = bhI << 17;
          #pragma unroll
          for (int j = 0; j < 4; ++j)
            Qb[base + (size_t)(ss + j) * 64 + dd] = (short)f2bf(acc[mi][ni][j] + bsv);
        } else if (z == 1) {
          // K fragment granules: [bh][t][half*4+c][lane2=dh*32+lr][e], e along d
          int c = dd >> 4, dh = (dd >> 3) & 1, e = dd & 7;
          int t = ss >> 6, half = (ss >> 5) & 1, lr = ss & 31;
          size_t g = (bhI * 32 + t) * 4096 + (size_t)(half * 4 + c) * 512 + e;
          #pragma unroll
          for (int j = 0; j < 4; ++j)
            Kb2[g + (size_t)(dh * 32 + lr + j) * 8] = (short)f2bf(acc[mi][ni][j] + bsv);
        } else {
          // V fragment granules: [bh][t][kc*2+dhalf][lane2=kh*32+lr][e], e along kpos
          int dhalf = dd >> 5, lr = dd & 31;
          int t = ss >> 6, ks = ss & 63;
          int kc = ks >> 4, kh = (ks >> 3) & 1, e0 = ks & 7;
          size_t g = (bhI * 32 + t) * 4096 + (size_t)(kc * 2 + dhalf) * 512 +
                     (size_t)(kh * 32 + lr) * 8 + e0;
          short4v pk;
          #pragma unroll
          for (int j = 0; j < 4; ++j) pk[j] = (short)f2bf(acc[mi][ni][j] + bsv);
          *(short4v*)&Vb2[g] = pk;
        }
      }
    }
  } else {
    #pragma unroll
    for (int ni = 0; ni < 4; ++ni) {
      int n = col0 + wc * 64 + ni * 16 + (lane & 15);
      float bsv = bias0[n];
      #pragma unroll
      for (int mi = 0; mi < 4; ++mi) {
        int rg = row0 + wr * 64 + mi * 16 + ((lane >> 4) << 2);
        #pragma unroll
        for (int j = 0; j < 4; ++j)
          outp[(size_t)(rg + j) * 512 + n] = acc[mi][ni][j] + bsv;
      }
    }
  }
}

// ---------------- kernel 4: flash attention ----------------
// 1-D grid 512 (XCD-swizzled), 512 threads = 4 q-groups x 2 k-segments.
// Fixed-m softmax: m set once from tile 0 (exact per-row max of tile 0);
// later tiles never rescale (exp2 arg bounded << 126, P <= ~20 is safe in
// bf16 with fp32 accum). Steady-state BODY: no max tree, no ballot, no branch.
__global__ __launch_bounds__(512) void sa_attn(const short* __restrict__ Qb,
                                               const short* __restrict__ Kb2,
                                               const short* __restrict__ Vb2,
                                               short* __restrict__ Ob) {
  __shared__ __align__(16) short K_lds[2][2][4096];   // [seg][buf] 8 KB tiles
  __shared__ __align__(16) short V_lds[2][2][4096];
  const int tid = threadIdx.x, lane = tid & 63, wave = tid >> 6;
  const int seg = wave >> 2, wq = wave & 3;
  const int dd0 = blockIdx.x;                 // 512 = 8 * 64, bijective
  const int wg = (dd0 & 7) * 64 + (dd0 >> 3); // all 16 q-tiles of a (b,h) pair on one XCD
  const int qb = wg & 15, hb = (wg >> 4) & 7, b = wg >> 7;
  const size_t bh32 = ((size_t)(b * NH_ + hb)) * 32;
  const int q0w = qb * 128 + wq * 32;
  const int l31 = lane & 31, hh = lane >> 5, base32 = lane & 32;
  const int stid = tid & 255;
  const int lo = lane * 8;
  const int sg16 = seg * 16;

  // Q frags (B-operand): q = q0w + l31, d = c*16 + hh*8 + {0..7}
  const size_t bhq = ((size_t)(b * NH_ + hb)) << 17;
  short8 qf[4];
  #pragma unroll
  for (int c = 0; c < 4; ++c)
    qf[c] = *(const short8*)&Qb[bhq + (size_t)(q0w + l31) * 64 + c * 16 + hh * 8];

  f32x16 o0 = {}, o1 = {};
  const f32x16 FZ = {};
  float mrow = 0.f, lpart = 0.f;           // lpart: per-lane partial (own 32 kpos)
  const float cf = 0.18033688011112042f;   // log2(e)/8

  auto STAGE_K = [&](int sbuf, int tg) {
    const short* Ks = Kb2 + (bh32 + tg) * 4096;
    gload_lds16(Ks + (size_t)stid * 8,         &K_lds[seg][sbuf][wq * 512]);
    gload_lds16(Ks + (size_t)(256 + stid) * 8, &K_lds[seg][sbuf][2048 + wq * 512]);
  };
  auto STAGE_V = [&](int sbuf, int tg) {
    const short* Vs = Vb2 + (bh32 + tg) * 4096;
    gload_lds16(Vs + (size_t)stid * 8,         &V_lds[seg][sbuf][wq * 512]);
    gload_lds16(Vs + (size_t)(256 + stid) * 8, &V_lds[seg][sbuf][2048 + wq * 512]);
  };
  auto QK = [&](int nbuf, f32x16& s0, f32x16& s1) {
    const short* Kt = &K_lds[seg][nbuf][0];
    __builtin_amdgcn_s_setprio(1);
    {
      short8 kf0 = *(const short8*)&Kt[lo];
      short8 kf1 = *(const short8*)&Kt[4 * 512 + lo];
      s0 = mfma32(kf0, qf[0], FZ);
      s1 = mfma32(kf1, qf[0], FZ);
    }
    #pragma unroll
    for (int c = 1; c < 4; ++c) {
      short8 kf0 = *(const short8*)&Kt[c * 512 + lo];
      short8 kf1 = *(const short8*)&Kt[(4 + c) * 512 + lo];
      s0 = mfma32(kf0, qf[c], s0);
      s1 = mfma32(kf1, qf[c], s1);
    }
    __builtin_amdgcn_s_setprio(0);
  };

  auto BODY = [&](f32x16& c0, f32x16& c1, f32x16& n0, f32x16& n1, int t,
                  bool domax) {
    const int buf = t & 1, nbuf = buf ^ 1;
    // staged stores: K two-ahead into buf, V one-ahead into nbuf (disjoint from
    // this iter's reads: QK reads K[nbuf], PV reads V[buf])
    if (t + 2 < 16) STAGE_K(buf, sg16 + t + 2);
    if (t + 1 < 16) {
      STAGE_V(nbuf, sg16 + t + 1);
      QK(nbuf, n0, n1);            // MFMA pipe crunches during softmax below
    }

    if (domax) {                   // tile 0 only: exact per-row max
      float mx = c0[0];
      #pragma unroll
      for (int r = 1; r < 16; ++r) mx = fmaxf(mx, c0[r]);
      #pragma unroll
      for (int r = 0; r < 16; ++r) mx = fmaxf(mx, c1[r]);
      u32x2 mm = pl32swap(__builtin_bit_cast(unsigned int, mx),
                          __builtin_bit_cast(unsigned int, mx));
      mrow = fmaxf(__builtin_bit_cast(float, mm[0]),
                   __builtin_bit_cast(float, mm[1]));
    }

    // ---- exp pass: P = exp2(sc*cf - mc), lane-local partial sums only ----
    const float mc = mrow * cf;
    float ps0 = 0.f, ps1 = 0.f, ps2 = 0.f, ps3 = 0.f;
    #pragma unroll
    for (int r = 0; r < 16; ++r) {
      float p0 = __builtin_amdgcn_exp2f(c0[r] * cf - mc);
      float p1 = __builtin_amdgcn_exp2f(c1[r] * cf - mc);
      c0[r] = p0; c1[r] = p1;
      if ((r & 3) == 0)      ps0 += p0 + p1;
      else if ((r & 3) == 1) ps1 += p0 + p1;
      else if ((r & 3) == 2) ps2 += p0 + p1;
      else                   ps3 += p0 + p1;
    }
    lpart += (ps0 + ps1) + (ps2 + ps3);

    // ---- pack P to bf16 words ----
    unsigned int W[16];
    #pragma unroll
    for (int m = 0; m < 4; ++m) {
      W[2 * m]         = packbf(c0[4 * m],     c0[4 * m + 1]);
      W[2 * m + 1]     = packbf(c0[4 * m + 2], c0[4 * m + 3]);
      W[8 + 2 * m]     = packbf(c1[4 * m],     c1[4 * m + 1]);
      W[8 + 2 * m + 1] = packbf(c1[4 * m + 2], c1[4 * m + 3]);
    }

    // ---- PV: o += P(32q x 64k) @ V(64k x 64d); frag halves via permlane32_swap
    const short* Vt = &V_lds[seg][buf][0];
    __builtin_amdgcn_s_setprio(1);
    #pragma unroll
    for (int kc = 0; kc < 4; ++kc) {
      u32x2 p02 = pl32swap(W[4 * kc],     W[4 * kc + 2]);
      u32x2 p13 = pl32swap(W[4 * kc + 1], W[4 * kc + 3]);
      u32x4 paw = {p02[0], p13[0], p02[1], p13[1]};
      short8 pa = __builtin_bit_cast(short8, paw);
      short8 vf0 = *(const short8*)&Vt[(kc * 2) * 512 + lo];
      short8 vf1 = *(const short8*)&Vt[(kc * 2 + 1) * 512 + lo];
      o0 = mfma32(pa, vf0, o0);
      o1 = mfma32(pa, vf1, o1);
    }
    __builtin_amdgcn_s_setprio(0);
    __syncthreads();   // drains stage loads; syncs buffer rotation
  };

  // prologue: K(0),K(1),V(0) staged; QK(0) computed
  STAGE_K(0, sg16);
  STAGE_K(1, sg16 + 1);
  STAGE_V(0, sg16);
  __syncthreads();
  f32x16 A0, A1, B0, B1;
  QK(0, A0, A1);
  __syncthreads();   // all waves done reading K[0] before BODY(0) overwrites it

  BODY(A0, A1, B0, B1, 0, true);
  for (int tt = 0; tt < 7; ++tt) {
    BODY(B0, B1, A0, A1, 2 * tt + 1, false);
    BODY(A0, A1, B0, B1, 2 * tt + 2, false);
  }
  BODY(B0, B1, A0, A1, 15, false);

  // ---- cross-half row sum (deferred from the loop) ----
  u32x2 lp = pl32swap(__builtin_bit_cast(unsigned int, lpart),
                      __builtin_bit_cast(unsigned int, lpart));
  float lrow = __builtin_bit_cast(float, lp[0]) + __builtin_bit_cast(float, lp[1]);

  // ---- combine the two k-segments via LDS, then write Ob ----
  float* Ml = (float*)&V_lds[0][0][0];   // 4 groups x 64 floats
  float* Ox = (float*)&K_lds[0][0][0];   // 4 groups x 2048 floats
  if (seg == 1) {
    if (lane < 32) { Ml[wq * 64 + lane] = mrow; Ml[wq * 64 + 32 + lane] = lrow; }
    float* Og = Ox + wq * 2048;
    #pragma unroll
    for (int r = 0; r < 16; ++r) {
      int qr = (r & 3) + 8 * (r >> 2) + 4 * hh;
      Og[qr * 64 + l31]      = o0[r];
      Og[qr * 64 + 32 + l31] = o1[r];
    }
  }
  __syncthreads();
  if (seg == 0) {
    float m1 = Ml[wq * 64 + l31], l1 = Ml[wq * 64 + 32 + l31];
    float M = fmaxf(mrow, m1);
    float a0 = __builtin_amdgcn_exp2f((mrow - M) * cf);
    float a1 = __builtin_amdgcn_exp2f((m1 - M) * cf);
    float inv = 1.f / (lrow * a0 + l1 * a1);
    float* Og = Ox + wq * 2048;
    #pragma unroll
    for (int r = 0; r < 16; ++r) {
      int qr = (r & 3) + 8 * (r >> 2) + 4 * hh;
      float A0b = __shfl(a0, base32 + qr);
      float A1b = __shfl(a1, base32 + qr);
      float I   = __shfl(inv, base32 + qr);
      float v0 = (o0[r] * A0b + Og[qr * 64 + l31] * A1b) * I;
      float v1 = (o1[r] * A0b + Og[qr * 64 + 32 + l31] * A1b) * I;
      size_t rowb = ((size_t)(b * S_ + q0w + qr)) * 512 + hb * 64;
      Ob[rowb + l31]      = (short)f2bf(v0);
      Ob[rowb + 32 + l31] = (short)f2bf(v1);
    }
  }
}

// ---------------- launcher ----------------
extern "C" void kernel_launch(void* const* d_in, const int* in_sizes, int n_in,
                              void* d_out, int out_size, void* d_ws, size_t ws_size,
                              hipStream_t stream) {
  const float* x  = (const float*)d_in[0];
  const float* Wq = (const float*)d_in[1];
  const float* bq = (const float*)d_in[2];
  const float* Wk = (const float*)d_in[3];
  const float* bk = (const float*)d_in[4];
  const float* Wv = (const float*)d_in[5];
  const float* bv = (const float*)d_in[6];
  const float* Wo = (const float*)d_in[7];
  const float* bo = (const float*)d_in[8];
  float* out = (float*)d_out;

  short* ws = (short*)d_ws;
  short* xb  = ws;                  // 8192*512  = 4,194,304 shorts
  short* Wt  = ws + 4194304;        // 4*512*512 = 1,048,576
  short* Qb  = ws + 5242880;        // (B,H,S,D) = 4,194,304
  short* Kb2 = ws + 9437184;        // K fragment-order = 4,194,304
  short* Vb2 = ws + 13631488;       // V fragment-order = 4,194,304
  short* Ob  = ws + 17825792;       // (B*S, 512) = 4,194,304  (end: 44 MB)

  hipLaunchKernelGGL(sa_convert_x, dim3(2048), dim3(256), 0, stream, x, xb);
  hipLaunchKernelGGL(sa_transpose_w, dim3(16, 16, 4), dim3(32, 8), 0, stream,
                     Wq, Wk, Wv, Wo, Wt);
  hipLaunchKernelGGL(sa_gemm<0>, dim3(768), dim3(256), 0, stream,
                     xb, Wt, bq, bk, bv, Qb, Kb2, Vb2, (float*)nullptr);
  hipLaunchKernelGGL(sa_attn, dim3(512), dim3(512), 0, stream, Qb, Kb2, Vb2, Ob);
  hipLaunchKernelGGL(sa_gemm<1>, dim3(256), dim3(256), 0, stream,
                     Ob, Wt, bo, (const float*)nullptr, (const float*)nullptr,
                     (short*)nullptr, (short*)nullptr, (short*)nullptr, out);
}